// Round 4
// baseline (148.947 us; speedup 1.0000x reference)
//
#include <hip/hip_runtime.h>
#include <hip/hip_bf16.h>

typedef unsigned long long ull;

#define MGRID 48
#define CCH   256
#define NCELL 2304      // 48*48
#define NA    6912      // anchors
#define NW    108       // NA/64
#define NHID  1024
#define KFC   2304      // 9*256
#define RPOST 512
#define IMGF  1536.0f

typedef __attribute__((ext_vector_type(8))) short short8v;  // 8 bf16
typedef __attribute__((ext_vector_type(4))) float f32x4;

// ---------------- K1: RPN head: per (cell, o) dot product ----------------
__global__ __launch_bounds__(256) void rpn_head(const float* __restrict__ feat,
    const float* __restrict__ Wobj, const float* __restrict__ bobj,
    const float* __restrict__ Wreg, const float* __restrict__ breg,
    float* __restrict__ rpn){
  int g = blockIdx.x*256 + threadIdx.x;   // 2304*18 = 41472 threads
  int cell = g / 18, o = g % 18;
  const float* x = feat + cell*CCH;
  const float* W; int stride; float acc;
  if (o < 6){ W = Wobj + o; stride = 6;  acc = bobj[o];   }
  else      { W = Wreg + (o-6); stride = 12; acc = breg[o-6]; }
  #pragma unroll 8
  for (int c=0;c<CCH;++c) acc += x[c]*W[c*stride];
  rpn[cell*18 + o] = acc;
}

// ---------------- K2: per-anchor softmax, box decode, sort key ----------------
__global__ __launch_bounds__(256) void anchor_prep(const float* __restrict__ rpn,
    const float* __restrict__ anchors, float* __restrict__ probs,
    float* __restrict__ boxes, ull* __restrict__ keys){
  int a = blockIdx.x*256 + threadIdx.x;   // 6912
  int cell = a/3, k = a%3;
  const float* rc = rpn + cell*18;
  float l0 = rc[2*k], l1 = rc[2*k+1];
  float m  = fmaxf(l0,l1);
  float e0 = expf(l0-m), e1 = expf(l1-m);
  float s  = e0 + e1;
  float p0 = e0/s, p1 = e1/s;
  probs[a*2+0] = p0; probs[a*2+1] = p1;
  float4 an = ((const float4*)anchors)[a];
  float r0 = rc[6+4*k+0], r1 = rc[6+4*k+1], r2 = rc[6+4*k+2], r3 = rc[6+4*k+3];
  float cxa = an.x + an.z*0.5f, cya = an.y + an.w*0.5f;
  float cx = r0*an.z + cxa, cy = r1*an.w + cya;
  float w  = an.z*expf(r2),  hh = an.w*expf(r3);
  float bx = cx - w*0.5f, by = cy - hh*0.5f;
  float x1 = fminf(fmaxf(bx,      0.0f), IMGF);
  float y1 = fminf(fmaxf(by,      0.0f), IMGF);
  float x2 = fminf(fmaxf(bx + w,  0.0f), IMGF);
  float y2 = fminf(fmaxf(by + hh, 0.0f), IMGF);
  float4 bo; bo.x = x1; bo.y = y1; bo.z = x2 - x1; bo.w = y2 - y1;
  ((float4*)boxes)[a] = bo;
  // descending score, ties -> lower index first (stable argsort semantics)
  keys[a] = ((ull)__float_as_uint(p1) << 32) | (unsigned)(NA-1-a);
}

// ---------------- K3a: partial ranks: part[jb][i] = #{j in tile jb : key[j] > key[i]} ----------------
__global__ __launch_bounds__(256) void rank_part(const ull* __restrict__ keys,
                                                 int* __restrict__ part){
  __shared__ ull lk[256];
  int t = threadIdx.x;
  int ib = blockIdx.x, jb = blockIdx.y;
  lk[t] = keys[jb*256 + t];
  int i = ib*256 + t;
  ull ki = keys[i];
  __syncthreads();
  int cnt = 0;
  #pragma unroll 16
  for (int j=0;j<256;++j) cnt += (lk[j] > ki) ? 1 : 0;
  part[jb*NA + i] = cnt;
}

// ---------------- K3b: sum partials -> rank, scatter ord + sorted boxes ----------------
__global__ __launch_bounds__(256) void rank_scatter(const int* __restrict__ part,
    const float* __restrict__ boxes, int* __restrict__ ord, float* __restrict__ sboxes){
  int i = blockIdx.x*256 + threadIdx.x;
  int r = 0;
  #pragma unroll
  for (int jb=0;jb<27;++jb) r += part[jb*NA + i];
  ord[r] = i;
  ((float4*)sboxes)[r] = ((const float4*)boxes)[i];
}

// ---------------- K4: IoU suppression bitmask (transposed layout) ----------------
// maskT[w*NA + i] : bit jj set iff IoU(box_i, box_{w*64+jj}) > 0.3
__global__ __launch_bounds__(256) void iou_mask(const float* __restrict__ sboxes,
                                                ull* __restrict__ maskT){
  int gid = blockIdx.x*256 + threadIdx.x;  // 6912*108 threads
  int i = gid % NA;
  int w = gid / NA;
  float4 bi = ((const float4*)sboxes)[i];
  float x1i = bi.x, y1i = bi.y;
  float x2i = bi.x + bi.z, y2i = bi.y + bi.w;
  float ai  = (x2i - x1i) * (y2i - y1i);
  const float4* bj4 = (const float4*)sboxes + w*64;
  ull bits = 0;
  #pragma unroll 8
  for (int jj=0;jj<64;++jj){
    float4 bj = bj4[jj];                      // uniform across wave -> broadcast
    float x1j = bj.x, y1j = bj.y;
    float x2j = bj.x + bj.z, y2j = bj.y + bj.w;
    float aj  = (x2j - x1j) * (y2j - y1j);
    float iw = fmaxf(fminf(x2i,x2j) - fmaxf(x1i,x1j), 0.0f);
    float ih = fmaxf(fminf(y2i,y2j) - fmaxf(y1i,y1j), 0.0f);
    float inter = iw*ih;
    float den = ai + aj - inter + 1e-8f;
    if (inter > 0.3f*den) bits |= (1ull<<jj);
  }
  maskT[(size_t)w*NA + i] = bits;
}

// ---------------- K5: fused NMS (block 0) + W_fc1 transpose/cvt (blocks 1..2304) ----------------
// NMS: per 64-chunk, wave0 resolves keep-set via ballot fixpoint (registers only,
// IoU symmetry => lane t's suppressor set = own diag row masked to earlier bits).
// remv[c+1] updated urgently (prefetched word + LDS atomicOr); remv[c+2..] deferred
// to waves 1-3 during the NEXT chunk (off critical path, kb-masked loads).
__global__ __launch_bounds__(256) void nms_wcvt(const ull* __restrict__ maskT,
    const int* __restrict__ ord, const float* __restrict__ sboxes,
    const float* __restrict__ probs, const float* __restrict__ Wfc1,
    ushort* __restrict__ Wt, float* __restrict__ out, float* __restrict__ selb){
  if (blockIdx.x != 0){
    // ---- wcvt: transpose W_fc1 [KFC][NHID] -> Wt [NHID][KFC], f32->bf16 ----
    __shared__ float tile[32][33];
    int bid = blockIdx.x - 1;
    int bx = bid & 31;          // n-tile (32 cols of W), 32
    int by = bid >> 5;          // k-tile (32 rows of W), 72
    int tx = threadIdx.x & 31, ty = threadIdx.x >> 5;
    #pragma unroll
    for (int it=0; it<4; ++it)
      tile[ty + 8*it][tx] = Wfc1[(size_t)(by*32 + ty + 8*it)*NHID + bx*32 + tx];
    __syncthreads();
    #pragma unroll
    for (int it=0; it<4; ++it){
      __hip_bfloat16 b = __float2bfloat16(tile[tx][ty + 8*it]);
      Wt[(size_t)(bx*32 + ty + 8*it)*KFC + by*32 + tx] = *(ushort*)&b;
    }
    return;
  }

  __shared__ ull remv[NW];
  __shared__ ull keepw[NW];
  __shared__ ull kb_sh[2];
  __shared__ int selpos[RPOST];
  __shared__ int cnt_sh, done_sh;
  int t = threadIdx.x;
  if (t < NW){ remv[t] = 0ull; keepw[t] = 0ull; }
  if (t == 0){ cnt_sh = 0; done_sh = 0; kb_sh[0] = 0ull; kb_sh[1] = 0ull; }
  __syncthreads();

  ull dg_reg = 0, urg_reg = 0;
  if (t < 64){
    dg_reg  = maskT[t];                 // chunk 0 diag row (coalesced)
    urg_reg = maskT[(size_t)NA + t];    // chunk 0 -> remv[1] word
  }

  for (int c = 0; c < NW; ++c){
    if (t < 64){
      ull dg = dg_reg, urg = urg_reg;
      if (c+1 < NW){                    // prefetch chunk c+1 (hidden under fixpoint)
        dg_reg  = maskT[(size_t)(c+1)*NA + (size_t)(c+1)*64 + t];
        urg_reg = (c+2 < NW) ? maskT[(size_t)(c+2)*NA + (size_t)(c+1)*64 + t] : 0ull;
      }
      ull w0 = remv[c];                 // final: urgent(c-1) + deferred(<=c-2) landed
      bool decided = (w0 >> t) & 1ull;
      bool kept = false;
      ull sup = dg & ((1ull << t) - 1ull);   // earlier in-chunk suppressors (symmetric IoU)
      for (;;){
        ull K = __ballot(kept);
        ull D = __ballot(decided);
        if (D == ~0ull) break;          // each round decides >= lowest undecided lane
        if (!decided){
          if (sup & K)                { decided = true; }
          else if ((sup & ~D) == 0ull){ decided = true; kept = true; }
        }
      }
      ull kb = __ballot(kept);
      if (c+1 < NW && kept) atomicOr(&remv[c+1], urg);   // urgent word
      int cnt0 = cnt_sh;
      ull below = kb & ((1ull << t) - 1ull);
      int myrank = cnt0 + __popcll(below);
      if (kept && myrank < RPOST) selpos[myrank] = c*64 + t;
      if (t == 0){
        kb_sh[c & 1] = kb;
        keepw[c] = kb;
        int nc = cnt0 + __popcll(kb);
        if (nc >= RPOST){ nc = RPOST; done_sh = 1; }
        cnt_sh = nc;
      }
    } else {
      // deferred(c-1): OR kept rows of chunk c-1 into remv[c+1 .. NW-1]
      int u = t - 64;
      int wp = c + 1 + u;
      ull kbp = kb_sh[(c+1) & 1];       // kb of chunk c-1  ((c-1)&1 == (c+1)&1)
      if (c >= 1 && wp < NW && kbp){
        const ull* row = maskT + (size_t)wp*NA + (size_t)(c-1)*64;
        ull acc = 0, rem = kbp;
        while (rem){                     // uniform scalar loop: only kept bits load
          int b = __ffsll(rem) - 1;
          rem &= rem - 1;
          acc |= row[b];
        }
        if (acc) atomicOr(&remv[wp], acc);
      }
    }
    __syncthreads();
    if (done_sh) break;                 // top-512 complete: uniform exit
  }
  __syncthreads();
  // fill path (only when full scan finished with <512 kept): suppressed, ascending
  if (t == 0 && cnt_sh < RPOST){
    int cnt = cnt_sh;
    for (int p=0; p<NA && cnt<RPOST; ++p)
      if (!((keepw[p>>6] >> (p&63)) & 1ull)) selpos[cnt++] = p;
    cnt_sh = cnt;
  }
  __syncthreads();
  for (int s=t; s<RPOST; s+=256){
    int pos = selpos[s];
    int orig = ord[pos];
    float4 b = ((const float4*)sboxes)[pos];
    out[s*10+0] = probs[orig*2+0];
    out[s*10+1] = probs[orig*2+1];
    out[s*10+2] = b.x; out[s*10+3] = b.y; out[s*10+4] = b.z; out[s*10+5] = b.w;
    ((float4*)selb)[s] = b;
  }
}

// ---------------- K7: ROIAlign (block = box, thread = channel) -> bf16 pooled ----------------
__global__ __launch_bounds__(256) void roialign(const float* __restrict__ feat,
    const float* __restrict__ selb, __hip_bfloat16* __restrict__ pooled){
  int r = blockIdx.x, c = threadIdx.x;
  float4 b = ((const float4*)selb)[r];
  int x0[6], x1[6], y0[6], y1[6];
  float wx[6], wy[6];
  #pragma unroll
  for (int s=0;s<6;++s){
    float off = ((float)s + 0.5f) / 6.0f;
    float fx = (b.x + off*b.z) / 32.0f - 0.5f;
    fx = fminf(fmaxf(fx, 0.0f), 47.0f);
    int xx0 = (int)floorf(fx);
    x0[s] = xx0; x1[s] = min(xx0+1, 47); wx[s] = fx - (float)xx0;
    float fy = (b.y + off*b.w) / 32.0f - 0.5f;
    fy = fminf(fmaxf(fy, 0.0f), 47.0f);
    int yy0 = (int)floorf(fy);
    y0[s] = yy0; y1[s] = min(yy0+1, 47); wy[s] = fy - (float)yy0;
  }
  #pragma unroll
  for (int ty=0;ty<3;++ty){
    #pragma unroll
    for (int tx=0;tx<3;++tx){
      float sum = 0.0f;
      #pragma unroll
      for (int py=0;py<2;++py){
        #pragma unroll
        for (int px=0;px<2;++px){
          int sy = ty*2+py, sx = tx*2+px;
          float wxx = wx[sx], wyy = wy[sy];
          float v00 = feat[(y0[sy]*MGRID + x0[sx])*CCH + c];
          float v01 = feat[(y0[sy]*MGRID + x1[sx])*CCH + c];
          float v10 = feat[(y1[sy]*MGRID + x0[sx])*CCH + c];
          float v11 = feat[(y1[sy]*MGRID + x1[sx])*CCH + c];
          sum += v00*(1.0f-wyy)*(1.0f-wxx) + v01*(1.0f-wyy)*wxx
               + v10*wyy*(1.0f-wxx)        + v11*wyy*wxx;
        }
      }
      pooled[((r*9) + ty*3 + tx)*CCH + c] = __float2bfloat16(sum * 0.25f);
    }
  }
}

// ---------------- K8: FC1 bf16 MFMA: (512x2304) @ (2304x1024) + bias + ReLU ----------------
// A = pooled bf16 [512][2304]; Bt = Wt bf16 [1024][2304] (transposed); H f32 [512][1024]
__global__ __launch_bounds__(256) void fc1_mfma(const ushort* __restrict__ A,
    const ushort* __restrict__ Bt, const float* __restrict__ bias,
    float* __restrict__ H){
  __shared__ ushort As[4096];   // 64 rows x 64 k bf16, XOR-swizzled 16B chunks
  __shared__ ushort Bs[4096];
  const int t = threadIdx.x;
  const int bn = blockIdx.x, bm = blockIdx.y;
  const int wv = t >> 6, lane = t & 63;
  const int wm = (wv >> 1) * 32, wn = (wv & 1) * 32;

  // staging: 16B chunk s in {t, t+256}; row = s>>3, kchunk = s&7
  const int r0 = t >> 3, kc = t & 7;
  const int r1 = r0 + 32;
  const float4* gA0 = (const float4*)A  + (size_t)(bm*64 + r0)*288 + kc;  // 288 = 2304*2B/16B
  const float4* gA1 = (const float4*)A  + (size_t)(bm*64 + r1)*288 + kc;
  const float4* gB0 = (const float4*)Bt + (size_t)(bn*64 + r0)*288 + kc;
  const float4* gB1 = (const float4*)Bt + (size_t)(bn*64 + r1)*288 + kc;
  float4* sA0 = (float4*)As + ((r0<<3) | (kc ^ (r0&7)));
  float4* sA1 = (float4*)As + ((r1<<3) | (kc ^ (r1&7)));
  float4* sB0 = (float4*)Bs + ((r0<<3) | (kc ^ (r0&7)));
  float4* sB1 = (float4*)Bs + ((r1<<3) | (kc ^ (r1&7)));

  const int fr = lane & 15, fkg = lane >> 4;
  const int arow0 = wm + fr,      arow1 = wm + 16 + fr;
  const int brow0 = wn + fr,      brow1 = wn + 16 + fr;

  f32x4 acc00{}, acc01{}, acc10{}, acc11{};

  float4 pa0 = gA0[0], pa1 = gA1[0], pb0 = gB0[0], pb1 = gB1[0];
  for (int kt = 0; kt < KFC/64; ++kt){
    __syncthreads();                          // previous compute done; LDS writable
    *sA0 = pa0; *sA1 = pa1; *sB0 = pb0; *sB1 = pb1;
    if (kt + 1 < KFC/64){                     // T14: issue next tile's loads early
      pa0 = gA0[(kt+1)*8]; pa1 = gA1[(kt+1)*8];
      pb0 = gB0[(kt+1)*8]; pb1 = gB1[(kt+1)*8];
    }
    __syncthreads();                          // LDS tile ready
    #pragma unroll
    for (int kk2 = 0; kk2 < 2; ++kk2){
      int kidx = fkg + kk2*4;
      short8v a0 = *(const short8v*)(As + ((((arow0<<3) | (kidx ^ (arow0&7)))) << 3));
      short8v a1 = *(const short8v*)(As + ((((arow1<<3) | (kidx ^ (arow1&7)))) << 3));
      short8v b0 = *(const short8v*)(Bs + ((((brow0<<3) | (kidx ^ (brow0&7)))) << 3));
      short8v b1 = *(const short8v*)(Bs + ((((brow1<<3) | (kidx ^ (brow1&7)))) << 3));
      acc00 = __builtin_amdgcn_mfma_f32_16x16x32_bf16(a0, b0, acc00, 0, 0, 0);
      acc01 = __builtin_amdgcn_mfma_f32_16x16x32_bf16(a0, b1, acc01, 0, 0, 0);
      acc10 = __builtin_amdgcn_mfma_f32_16x16x32_bf16(a1, b0, acc10, 0, 0, 0);
      acc11 = __builtin_amdgcn_mfma_f32_16x16x32_bf16(a1, b1, acc11, 0, 0, 0);
    }
  }
  // epilogue: C/D layout col=lane&15, row=(lane>>4)*4+reg  [m89/m91 verified]
  const int orow = bm*64 + wm + (lane>>4)*4;
  const int ocol = bn*64 + wn + (lane&15);
  #pragma unroll
  for (int i=0;i<2;++i){
    #pragma unroll
    for (int j=0;j<2;++j){
      f32x4 a = (i==0) ? ((j==0)?acc00:acc01) : ((j==0)?acc10:acc11);
      #pragma unroll
      for (int reg=0;reg<4;++reg){
        int row = orow + i*16 + reg;
        int col = ocol + j*16;
        float v = a[reg] + bias[col];
        H[(size_t)row*NHID + col] = fmaxf(v, 0.0f);
      }
    }
  }
}

// ---------------- K9: FC2 + unparameterize (one wave per ROI) ----------------
__global__ __launch_bounds__(64) void fc2(const float* __restrict__ h,
    const float* __restrict__ W2, const float* __restrict__ b2,
    const float* __restrict__ selb, float* __restrict__ out){
  int r = blockIdx.x, lane = threadIdx.x;
  float a0=0,a1=0,a2=0,a3=0;
  #pragma unroll 4
  for (int it=0; it<16; ++it){
    int k = it*64 + lane;
    float hv = h[(size_t)r*NHID + k];
    float4 w = ((const float4*)W2)[k];
    a0 += hv*w.x; a1 += hv*w.y; a2 += hv*w.z; a3 += hv*w.w;
  }
  #pragma unroll
  for (int off=32; off>0; off>>=1){
    a0 += __shfl_down(a0, off);
    a1 += __shfl_down(a1, off);
    a2 += __shfl_down(a2, off);
    a3 += __shfl_down(a3, off);
  }
  if (lane == 0){
    float4 b = ((const float4*)selb)[r];
    float r0 = a0 + b2[0], r1 = a1 + b2[1], r2 = a2 + b2[2], r3 = a3 + b2[3];
    float cxa = b.x + b.z*0.5f, cya = b.y + b.w*0.5f;
    float cx = r0*b.z + cxa, cy = r1*b.w + cya;
    float w  = b.z*expf(r2),  hh = b.w*expf(r3);
    out[r*10+6] = cx - w*0.5f;
    out[r*10+7] = cy - hh*0.5f;
    out[r*10+8] = w;
    out[r*10+9] = hh;
  }
}

extern "C" void kernel_launch(void* const* d_in, const int* in_sizes, int n_in,
                              void* d_out, int out_size, void* d_ws, size_t ws_size,
                              hipStream_t stream) {
  const float* feat    = (const float*)d_in[0];
  const float* anchors = (const float*)d_in[1];
  const float* Wobj    = (const float*)d_in[2];
  const float* bobj    = (const float*)d_in[3];
  const float* Wreg    = (const float*)d_in[4];
  const float* breg    = (const float*)d_in[5];
  const float* Wfc1    = (const float*)d_in[6];
  const float* bfc1    = (const float*)d_in[7];
  const float* Wfc2    = (const float*)d_in[8];
  const float* bfc2    = (const float*)d_in[9];
  float* out = (float*)d_out;
  char* ws = (char*)d_ws;

  float* rpn    = (float*)(ws + 0);          // 165888
  float* probs  = (float*)(ws + 165888);     // 55296
  float* boxes  = (float*)(ws + 221184);     // 110592
  ull*   keys   = (ull*)  (ws + 331776);     // 55296
  int*   ord    = (int*)  (ws + 387072);     // 27648
  float* sboxes = (float*)(ws + 414720);     // 110592
  int*   part   = (int*)  (ws + 525312);     // 746496 (dead after rank_scatter)
  ull*   maskT  = (ull*)  (ws + 1271808);    // 5971968 (live through nms)
  float* selb   = (float*)(ws + 7243776);    // 8192
  __hip_bfloat16* pooled = (__hip_bfloat16*)(ws + 7251968); // 2359296
  float* h      = (float*)(ws + 9611264);    // 2097152
  ushort* Wt    = (ushort*)(ws + 11708416);  // 4718592 (own space: concurrent with maskT; end 16427008)

  hipLaunchKernelGGL(rpn_head,     dim3(162),     dim3(256), 0, stream, feat, Wobj, bobj, Wreg, breg, rpn);
  hipLaunchKernelGGL(anchor_prep,  dim3(27),      dim3(256), 0, stream, rpn, anchors, probs, boxes, keys);
  hipLaunchKernelGGL(rank_part,    dim3(27,27),   dim3(256), 0, stream, keys, part);
  hipLaunchKernelGGL(rank_scatter, dim3(27),      dim3(256), 0, stream, part, boxes, ord, sboxes);
  hipLaunchKernelGGL(iou_mask,     dim3(2916),    dim3(256), 0, stream, sboxes, maskT);
  hipLaunchKernelGGL(nms_wcvt,     dim3(2305),    dim3(256), 0, stream, maskT, ord, sboxes, probs, Wfc1, Wt, out, selb);
  hipLaunchKernelGGL(roialign,     dim3(512),     dim3(256), 0, stream, feat, selb, pooled);
  hipLaunchKernelGGL(fc1_mfma,     dim3(16,8),    dim3(256), 0, stream, (const ushort*)pooled, Wt, bfc1, h);
  hipLaunchKernelGGL(fc2,          dim3(512),     dim3(64),  0, stream, h, Wfc2, bfc2, selb, out);
}

// Round 5
// 124.153 us; speedup vs baseline: 1.1997x; 1.1997x over previous
//
#include <hip/hip_runtime.h>
#include <hip/hip_bf16.h>

typedef unsigned long long ull;

#define MGRID 48
#define CCH   256
#define NCELL 2304      // 48*48
#define NA    6912      // anchors
#define NW    108       // NA/64
#define NHID  1024
#define KFC   2304      // 9*256
#define RPOST 512
#define IMGF  1536.0f

typedef __attribute__((ext_vector_type(8))) short short8v;  // 8 bf16
typedef __attribute__((ext_vector_type(4))) float f32x4;

__device__ inline ull shfl64(ull v, int lane){
  unsigned lo = (unsigned)__shfl((int)(unsigned)(v & 0xffffffffull), lane);
  unsigned hi = (unsigned)__shfl((int)(unsigned)(v >> 32), lane);
  return ((ull)hi << 32) | (ull)lo;
}

// ---------------- K1: RPN head: per (cell, o) dot product ----------------
__global__ __launch_bounds__(256) void rpn_head(const float* __restrict__ feat,
    const float* __restrict__ Wobj, const float* __restrict__ bobj,
    const float* __restrict__ Wreg, const float* __restrict__ breg,
    float* __restrict__ rpn){
  int g = blockIdx.x*256 + threadIdx.x;   // 2304*18 = 41472 threads
  int cell = g / 18, o = g % 18;
  const float* x = feat + cell*CCH;
  const float* W; int stride; float acc;
  if (o < 6){ W = Wobj + o; stride = 6;  acc = bobj[o];   }
  else      { W = Wreg + (o-6); stride = 12; acc = breg[o-6]; }
  #pragma unroll 8
  for (int c=0;c<CCH;++c) acc += x[c]*W[c*stride];
  rpn[cell*18 + o] = acc;
}

// ---------------- K2: per-anchor softmax, box decode, sort key ----------------
__global__ __launch_bounds__(256) void anchor_prep(const float* __restrict__ rpn,
    const float* __restrict__ anchors, float* __restrict__ probs,
    float* __restrict__ boxes, ull* __restrict__ keys){
  int a = blockIdx.x*256 + threadIdx.x;   // 6912
  int cell = a/3, k = a%3;
  const float* rc = rpn + cell*18;
  float l0 = rc[2*k], l1 = rc[2*k+1];
  float m  = fmaxf(l0,l1);
  float e0 = expf(l0-m), e1 = expf(l1-m);
  float s  = e0 + e1;
  float p0 = e0/s, p1 = e1/s;
  probs[a*2+0] = p0; probs[a*2+1] = p1;
  float4 an = ((const float4*)anchors)[a];
  float r0 = rc[6+4*k+0], r1 = rc[6+4*k+1], r2 = rc[6+4*k+2], r3 = rc[6+4*k+3];
  float cxa = an.x + an.z*0.5f, cya = an.y + an.w*0.5f;
  float cx = r0*an.z + cxa, cy = r1*an.w + cya;
  float w  = an.z*expf(r2),  hh = an.w*expf(r3);
  float bx = cx - w*0.5f, by = cy - hh*0.5f;
  float x1 = fminf(fmaxf(bx,      0.0f), IMGF);
  float y1 = fminf(fmaxf(by,      0.0f), IMGF);
  float x2 = fminf(fmaxf(bx + w,  0.0f), IMGF);
  float y2 = fminf(fmaxf(by + hh, 0.0f), IMGF);
  float4 bo; bo.x = x1; bo.y = y1; bo.z = x2 - x1; bo.w = y2 - y1;
  ((float4*)boxes)[a] = bo;
  // descending score, ties -> lower index first (stable argsort semantics)
  keys[a] = ((ull)__float_as_uint(p1) << 32) | (unsigned)(NA-1-a);
}

// ---------------- K3a: partial ranks: part[jb][i] = #{j in tile jb : key[j] > key[i]} ----------------
__global__ __launch_bounds__(256) void rank_part(const ull* __restrict__ keys,
                                                 int* __restrict__ part){
  __shared__ ull lk[256];
  int t = threadIdx.x;
  int ib = blockIdx.x, jb = blockIdx.y;
  lk[t] = keys[jb*256 + t];
  int i = ib*256 + t;
  ull ki = keys[i];
  __syncthreads();
  int cnt = 0;
  #pragma unroll 16
  for (int j=0;j<256;++j) cnt += (lk[j] > ki) ? 1 : 0;
  part[jb*NA + i] = cnt;
}

// ---------------- K3b: sum partials -> rank, scatter ord + sorted boxes ----------------
__global__ __launch_bounds__(256) void rank_scatter(const int* __restrict__ part,
    const float* __restrict__ boxes, int* __restrict__ ord, float* __restrict__ sboxes){
  int i = blockIdx.x*256 + threadIdx.x;
  int r = 0;
  #pragma unroll
  for (int jb=0;jb<27;++jb) r += part[jb*NA + i];
  ord[r] = i;
  ((float4*)sboxes)[r] = ((const float4*)boxes)[i];
}

// ---------------- K4: IoU suppression bitmask (transposed layout) ----------------
// maskT[w*NA + i] : bit jj set iff IoU(box_i, box_{w*64+jj}) > 0.3
__global__ __launch_bounds__(256) void iou_mask(const float* __restrict__ sboxes,
                                                ull* __restrict__ maskT){
  int gid = blockIdx.x*256 + threadIdx.x;  // 6912*108 threads
  int i = gid % NA;
  int w = gid / NA;
  float4 bi = ((const float4*)sboxes)[i];
  float x1i = bi.x, y1i = bi.y;
  float x2i = bi.x + bi.z, y2i = bi.y + bi.w;
  float ai  = (x2i - x1i) * (y2i - y1i);
  const float4* bj4 = (const float4*)sboxes + w*64;
  ull bits = 0;
  #pragma unroll 8
  for (int jj=0;jj<64;++jj){
    float4 bj = bj4[jj];                      // uniform across wave -> broadcast
    float x1j = bj.x, y1j = bj.y;
    float x2j = bj.x + bj.z, y2j = bj.y + bj.w;
    float aj  = (x2j - x1j) * (y2j - y1j);
    float iw = fmaxf(fminf(x2i,x2j) - fmaxf(x1i,x1j), 0.0f);
    float ih = fmaxf(fminf(y2i,y2j) - fmaxf(y1i,y1j), 0.0f);
    float inter = iw*ih;
    float den = ai + aj - inter + 1e-8f;
    if (inter > 0.3f*den) bits |= (1ull<<jj);
  }
  maskT[(size_t)w*NA + i] = bits;
}

// ---------------- K5: fused NMS (block 0) + W_fc1 transpose/cvt (blocks 1..2304) ----------------
// Per 64-chunk c (ONE barrier per chunk):
//   wave0:   ffsll greedy scan (proven round-3 form) -> kb; urgent remv[c+1] via
//            coalesced row word + butterfly shfl-OR; selpos/bookkeeping; diag dbuf store.
//   waves1-3: deferred chunk c-1 -> remv[c+1..] via UNROLLED 64 independent masked
//            loads (issue-rate bound, overlaps wave0's scan).
// Fill path (<512 kept after all chunks) fully parallelized via per-word popcount
// prefix (was a 29us serial t==0 loop!).
__global__ __launch_bounds__(256) void nms_wcvt(const ull* __restrict__ maskT,
    const int* __restrict__ ord, const float* __restrict__ sboxes,
    const float* __restrict__ probs, const float* __restrict__ Wfc1,
    ushort* __restrict__ Wt, float* __restrict__ out, float* __restrict__ selb){
  if (blockIdx.x != 0){
    // ---- wcvt: transpose W_fc1 [KFC][NHID] -> Wt [NHID][KFC], f32->bf16 ----
    __shared__ float tile[32][33];
    int bid = blockIdx.x - 1;
    int bx = bid & 31;          // n-tile (32 cols of W), 32
    int by = bid >> 5;          // k-tile (32 rows of W), 72
    int tx = threadIdx.x & 31, ty = threadIdx.x >> 5;
    #pragma unroll
    for (int it=0; it<4; ++it)
      tile[ty + 8*it][tx] = Wfc1[(size_t)(by*32 + ty + 8*it)*NHID + bx*32 + tx];
    __syncthreads();
    #pragma unroll
    for (int it=0; it<4; ++it){
      __hip_bfloat16 b = __float2bfloat16(tile[tx][ty + 8*it]);
      Wt[(size_t)(bx*32 + ty + 8*it)*KFC + by*32 + tx] = *(ushort*)&b;
    }
    return;
  }

  __shared__ ull remv[NW];
  __shared__ ull keepw[NW];
  __shared__ ull diag_sh[2][64];
  __shared__ ull kb_sh[2];
  __shared__ int selpos[RPOST];
  __shared__ int base_sh[NW];
  __shared__ int cnt_sh, done_sh;
  int t = threadIdx.x;
  if (t < NW){ remv[t] = 0ull; keepw[t] = 0ull; }
  if (t == 0){ cnt_sh = 0; done_sh = 0; kb_sh[0] = 0ull; kb_sh[1] = 0ull; }
  if (t < 64) diag_sh[0][t] = maskT[t];      // diag rows of chunk 0
  __syncthreads();

  for (int c = 0; c < NW; ++c){
    if (t < 64){
      // prefetch next diag + urgent row word (addresses independent of scan)
      ull dreg = 0, urow = 0;
      if (c+1 < NW){
        dreg = maskT[(size_t)(c+1)*NA + (size_t)(c+1)*64 + t];
        urow = maskT[(size_t)(c+1)*NA + (size_t)c*64 + t];
      }
      // phase A: greedy ffsll scan over kept bits (serial, LDS broadcast)
      const ull* dg = diag_sh[c & 1];
      ull w = remv[c];
      ull kb = 0;
      ull avail = ~w;
      while (avail){
        int b = __ffsll(avail) - 1;
        kb |= 1ull << b;
        w |= dg[b];
        avail &= ~w;
      }
      // urgent: remv[c+1] |= OR of kept rows' word (butterfly across wave 0)
      ull um = ((kb >> t) & 1ull) ? urow : 0ull;
      #pragma unroll
      for (int off=1; off<64; off<<=1) um |= shfl64(um, t ^ off);
      if (t == 0 && c+1 < NW && um) atomicOr(&remv[c+1], um);
      // selpos + bookkeeping
      int cnt0 = cnt_sh;
      ull below = kb & ((1ull << t) - 1ull);
      int myrank = cnt0 + __popcll(below);
      if (((kb >> t) & 1ull) && myrank < RPOST) selpos[myrank] = c*64 + t;
      if (t == 0){
        kb_sh[c & 1] = kb;
        keepw[c] = kb;
        int nc = cnt0 + __popcll(kb);
        if (nc >= RPOST){ nc = RPOST; done_sh = 1; }
        cnt_sh = nc;
      }
      if (c+1 < NW) diag_sh[(c+1) & 1][t] = dreg;   // other buffer than dg: safe pre-barrier
    } else {
      // deferred: apply chunk c-1's kept rows to remv[c+1 .. ] (unrolled, independent loads)
      int u = t - 64;
      int wp = c + 1 + u;
      if (c >= 1 && wp < NW){
        ull kbp = kb_sh[(c-1) & 1];
        if (kbp){
          const ull* row = maskT + (size_t)wp*NA + (size_t)(c-1)*64;
          ull acc = 0;
          #pragma unroll
          for (int b=0;b<64;++b)
            acc |= (0ull - ((kbp >> b) & 1ull)) & row[b];
          if (acc) atomicOr(&remv[wp], acc);
        }
      }
    }
    __syncthreads();
    if (done_sh) break;                 // top-512 complete: uniform exit
  }
  __syncthreads();
  // parallel fill path (<512 kept after full scan): suppressed positions, ascending
  int cnt0 = cnt_sh;
  if (cnt0 < RPOST){
    if (t < NW){
      int s = 0;
      for (int w2=0; w2<t; ++w2) s += __popcll(~keepw[w2]);
      base_sh[t] = s;
    }
    __syncthreads();
    for (int p = t; p < NA; p += 256){
      int w2 = p >> 6, b = p & 63;
      ull kw = keepw[w2];
      if (!((kw >> b) & 1ull)){
        int rank = cnt0 + base_sh[w2] + __popcll(~kw & ((1ull << b) - 1ull));
        if (rank < RPOST) selpos[rank] = p;
      }
    }
  }
  __syncthreads();
  for (int s=t; s<RPOST; s+=256){
    int pos = selpos[s];
    int orig = ord[pos];
    float4 b = ((const float4*)sboxes)[pos];
    out[s*10+0] = probs[orig*2+0];
    out[s*10+1] = probs[orig*2+1];
    out[s*10+2] = b.x; out[s*10+3] = b.y; out[s*10+4] = b.z; out[s*10+5] = b.w;
    ((float4*)selb)[s] = b;
  }
}

// ---------------- K7: ROIAlign (block = box, thread = channel) -> bf16 pooled ----------------
__global__ __launch_bounds__(256) void roialign(const float* __restrict__ feat,
    const float* __restrict__ selb, __hip_bfloat16* __restrict__ pooled){
  int r = blockIdx.x, c = threadIdx.x;
  float4 b = ((const float4*)selb)[r];
  int x0[6], x1[6], y0[6], y1[6];
  float wx[6], wy[6];
  #pragma unroll
  for (int s=0;s<6;++s){
    float off = ((float)s + 0.5f) / 6.0f;
    float fx = (b.x + off*b.z) / 32.0f - 0.5f;
    fx = fminf(fmaxf(fx, 0.0f), 47.0f);
    int xx0 = (int)floorf(fx);
    x0[s] = xx0; x1[s] = min(xx0+1, 47); wx[s] = fx - (float)xx0;
    float fy = (b.y + off*b.w) / 32.0f - 0.5f;
    fy = fminf(fmaxf(fy, 0.0f), 47.0f);
    int yy0 = (int)floorf(fy);
    y0[s] = yy0; y1[s] = min(yy0+1, 47); wy[s] = fy - (float)yy0;
  }
  #pragma unroll
  for (int ty=0;ty<3;++ty){
    #pragma unroll
    for (int tx=0;tx<3;++tx){
      float sum = 0.0f;
      #pragma unroll
      for (int py=0;py<2;++py){
        #pragma unroll
        for (int px=0;px<2;++px){
          int sy = ty*2+py, sx = tx*2+px;
          float wxx = wx[sx], wyy = wy[sy];
          float v00 = feat[(y0[sy]*MGRID + x0[sx])*CCH + c];
          float v01 = feat[(y0[sy]*MGRID + x1[sx])*CCH + c];
          float v10 = feat[(y1[sy]*MGRID + x0[sx])*CCH + c];
          float v11 = feat[(y1[sy]*MGRID + x1[sx])*CCH + c];
          sum += v00*(1.0f-wyy)*(1.0f-wxx) + v01*(1.0f-wyy)*wxx
               + v10*wyy*(1.0f-wxx)        + v11*wyy*wxx;
        }
      }
      pooled[((r*9) + ty*3 + tx)*CCH + c] = __float2bfloat16(sum * 0.25f);
    }
  }
}

// ---------------- K8: FC1 bf16 MFMA: (512x2304) @ (2304x1024) + bias + ReLU ----------------
// A = pooled bf16 [512][2304]; Bt = Wt bf16 [1024][2304] (transposed); H f32 [512][1024]
__global__ __launch_bounds__(256) void fc1_mfma(const ushort* __restrict__ A,
    const ushort* __restrict__ Bt, const float* __restrict__ bias,
    float* __restrict__ H){
  __shared__ ushort As[4096];   // 64 rows x 64 k bf16, XOR-swizzled 16B chunks
  __shared__ ushort Bs[4096];
  const int t = threadIdx.x;
  const int bn = blockIdx.x, bm = blockIdx.y;
  const int wv = t >> 6, lane = t & 63;
  const int wm = (wv >> 1) * 32, wn = (wv & 1) * 32;

  // staging: 16B chunk s in {t, t+256}; row = s>>3, kchunk = s&7
  const int r0 = t >> 3, kc = t & 7;
  const int r1 = r0 + 32;
  const float4* gA0 = (const float4*)A  + (size_t)(bm*64 + r0)*288 + kc;  // 288 = 2304*2B/16B
  const float4* gA1 = (const float4*)A  + (size_t)(bm*64 + r1)*288 + kc;
  const float4* gB0 = (const float4*)Bt + (size_t)(bn*64 + r0)*288 + kc;
  const float4* gB1 = (const float4*)Bt + (size_t)(bn*64 + r1)*288 + kc;
  float4* sA0 = (float4*)As + ((r0<<3) | (kc ^ (r0&7)));
  float4* sA1 = (float4*)As + ((r1<<3) | (kc ^ (r1&7)));
  float4* sB0 = (float4*)Bs + ((r0<<3) | (kc ^ (r0&7)));
  float4* sB1 = (float4*)Bs + ((r1<<3) | (kc ^ (r1&7)));

  const int fr = lane & 15, fkg = lane >> 4;
  const int arow0 = wm + fr,      arow1 = wm + 16 + fr;
  const int brow0 = wn + fr,      brow1 = wn + 16 + fr;

  f32x4 acc00{}, acc01{}, acc10{}, acc11{};

  float4 pa0 = gA0[0], pa1 = gA1[0], pb0 = gB0[0], pb1 = gB1[0];
  for (int kt = 0; kt < KFC/64; ++kt){
    __syncthreads();                          // previous compute done; LDS writable
    *sA0 = pa0; *sA1 = pa1; *sB0 = pb0; *sB1 = pb1;
    if (kt + 1 < KFC/64){                     // T14: issue next tile's loads early
      pa0 = gA0[(kt+1)*8]; pa1 = gA1[(kt+1)*8];
      pb0 = gB0[(kt+1)*8]; pb1 = gB1[(kt+1)*8];
    }
    __syncthreads();                          // LDS tile ready
    #pragma unroll
    for (int kk2 = 0; kk2 < 2; ++kk2){
      int kidx = fkg + kk2*4;
      short8v a0 = *(const short8v*)(As + ((((arow0<<3) | (kidx ^ (arow0&7)))) << 3));
      short8v a1 = *(const short8v*)(As + ((((arow1<<3) | (kidx ^ (arow1&7)))) << 3));
      short8v b0 = *(const short8v*)(Bs + ((((brow0<<3) | (kidx ^ (brow0&7)))) << 3));
      short8v b1 = *(const short8v*)(Bs + ((((brow1<<3) | (kidx ^ (brow1&7)))) << 3));
      acc00 = __builtin_amdgcn_mfma_f32_16x16x32_bf16(a0, b0, acc00, 0, 0, 0);
      acc01 = __builtin_amdgcn_mfma_f32_16x16x32_bf16(a0, b1, acc01, 0, 0, 0);
      acc10 = __builtin_amdgcn_mfma_f32_16x16x32_bf16(a1, b0, acc10, 0, 0, 0);
      acc11 = __builtin_amdgcn_mfma_f32_16x16x32_bf16(a1, b1, acc11, 0, 0, 0);
    }
  }
  // epilogue: C/D layout col=lane&15, row=(lane>>4)*4+reg  [m89/m91 verified]
  const int orow = bm*64 + wm + (lane>>4)*4;
  const int ocol = bn*64 + wn + (lane&15);
  #pragma unroll
  for (int i=0;i<2;++i){
    #pragma unroll
    for (int j=0;j<2;++j){
      f32x4 a = (i==0) ? ((j==0)?acc00:acc01) : ((j==0)?acc10:acc11);
      #pragma unroll
      for (int reg=0;reg<4;++reg){
        int row = orow + i*16 + reg;
        int col = ocol + j*16;
        float v = a[reg] + bias[col];
        H[(size_t)row*NHID + col] = fmaxf(v, 0.0f);
      }
    }
  }
}

// ---------------- K9: FC2 + unparameterize (one wave per ROI) ----------------
__global__ __launch_bounds__(64) void fc2(const float* __restrict__ h,
    const float* __restrict__ W2, const float* __restrict__ b2,
    const float* __restrict__ selb, float* __restrict__ out){
  int r = blockIdx.x, lane = threadIdx.x;
  float a0=0,a1=0,a2=0,a3=0;
  #pragma unroll 4
  for (int it=0; it<16; ++it){
    int k = it*64 + lane;
    float hv = h[(size_t)r*NHID + k];
    float4 w = ((const float4*)W2)[k];
    a0 += hv*w.x; a1 += hv*w.y; a2 += hv*w.z; a3 += hv*w.w;
  }
  #pragma unroll
  for (int off=32; off>0; off>>=1){
    a0 += __shfl_down(a0, off);
    a1 += __shfl_down(a1, off);
    a2 += __shfl_down(a2, off);
    a3 += __shfl_down(a3, off);
  }
  if (lane == 0){
    float4 b = ((const float4*)selb)[r];
    float r0 = a0 + b2[0], r1 = a1 + b2[1], r2 = a2 + b2[2], r3 = a3 + b2[3];
    float cxa = b.x + b.z*0.5f, cya = b.y + b.w*0.5f;
    float cx = r0*b.z + cxa, cy = r1*b.w + cya;
    float w  = b.z*expf(r2),  hh = b.w*expf(r3);
    out[r*10+6] = cx - w*0.5f;
    out[r*10+7] = cy - hh*0.5f;
    out[r*10+8] = w;
    out[r*10+9] = hh;
  }
}

extern "C" void kernel_launch(void* const* d_in, const int* in_sizes, int n_in,
                              void* d_out, int out_size, void* d_ws, size_t ws_size,
                              hipStream_t stream) {
  const float* feat    = (const float*)d_in[0];
  const float* anchors = (const float*)d_in[1];
  const float* Wobj    = (const float*)d_in[2];
  const float* bobj    = (const float*)d_in[3];
  const float* Wreg    = (const float*)d_in[4];
  const float* breg    = (const float*)d_in[5];
  const float* Wfc1    = (const float*)d_in[6];
  const float* bfc1    = (const float*)d_in[7];
  const float* Wfc2    = (const float*)d_in[8];
  const float* bfc2    = (const float*)d_in[9];
  float* out = (float*)d_out;
  char* ws = (char*)d_ws;

  float* rpn    = (float*)(ws + 0);          // 165888
  float* probs  = (float*)(ws + 165888);     // 55296
  float* boxes  = (float*)(ws + 221184);     // 110592
  ull*   keys   = (ull*)  (ws + 331776);     // 55296
  int*   ord    = (int*)  (ws + 387072);     // 27648
  float* sboxes = (float*)(ws + 414720);     // 110592
  int*   part   = (int*)  (ws + 525312);     // 746496 (dead after rank_scatter)
  ull*   maskT  = (ull*)  (ws + 1271808);    // 5971968 (live through nms)
  float* selb   = (float*)(ws + 7243776);    // 8192
  __hip_bfloat16* pooled = (__hip_bfloat16*)(ws + 7251968); // 2359296
  float* h      = (float*)(ws + 9611264);    // 2097152
  ushort* Wt    = (ushort*)(ws + 11708416);  // 4718592 (own space: concurrent with maskT; end 16427008)

  hipLaunchKernelGGL(rpn_head,     dim3(162),     dim3(256), 0, stream, feat, Wobj, bobj, Wreg, breg, rpn);
  hipLaunchKernelGGL(anchor_prep,  dim3(27),      dim3(256), 0, stream, rpn, anchors, probs, boxes, keys);
  hipLaunchKernelGGL(rank_part,    dim3(27,27),   dim3(256), 0, stream, keys, part);
  hipLaunchKernelGGL(rank_scatter, dim3(27),      dim3(256), 0, stream, part, boxes, ord, sboxes);
  hipLaunchKernelGGL(iou_mask,     dim3(2916),    dim3(256), 0, stream, sboxes, maskT);
  hipLaunchKernelGGL(nms_wcvt,     dim3(2305),    dim3(256), 0, stream, maskT, ord, sboxes, probs, Wfc1, Wt, out, selb);
  hipLaunchKernelGGL(roialign,     dim3(512),     dim3(256), 0, stream, feat, selb, pooled);
  hipLaunchKernelGGL(fc1_mfma,     dim3(16,8),    dim3(256), 0, stream, (const ushort*)pooled, Wt, bfc1, h);
  hipLaunchKernelGGL(fc2,          dim3(512),     dim3(64),  0, stream, h, Wfc2, bfc2, selb, out);
}

// Round 6
// 122.903 us; speedup vs baseline: 1.2119x; 1.0102x over previous
//
#include <hip/hip_runtime.h>
#include <hip/hip_bf16.h>

typedef unsigned long long ull;

#define MGRID 48
#define CCH   256
#define NCELL 2304      // 48*48
#define NA    6912      // anchors
#define NW    108       // NA/64
#define NHID  1024
#define KFC   2304      // 9*256
#define RPOST 512
#define IMGF  1536.0f

typedef __attribute__((ext_vector_type(8))) short short8v;  // 8 bf16
typedef __attribute__((ext_vector_type(4))) float f32x4;

// ---------------- K1: RPN head: per (cell, o) dot product ----------------
__global__ __launch_bounds__(256) void rpn_head(const float* __restrict__ feat,
    const float* __restrict__ Wobj, const float* __restrict__ bobj,
    const float* __restrict__ Wreg, const float* __restrict__ breg,
    float* __restrict__ rpn){
  int g = blockIdx.x*256 + threadIdx.x;   // 2304*18 = 41472 threads
  int cell = g / 18, o = g % 18;
  const float* x = feat + cell*CCH;
  const float* W; int stride; float acc;
  if (o < 6){ W = Wobj + o; stride = 6;  acc = bobj[o];   }
  else      { W = Wreg + (o-6); stride = 12; acc = breg[o-6]; }
  #pragma unroll 8
  for (int c=0;c<CCH;++c) acc += x[c]*W[c*stride];
  rpn[cell*18 + o] = acc;
}

// ---------------- K2: per-anchor softmax, box decode, sort key ----------------
__global__ __launch_bounds__(256) void anchor_prep(const float* __restrict__ rpn,
    const float* __restrict__ anchors, float* __restrict__ probs,
    float* __restrict__ boxes, ull* __restrict__ keys){
  int a = blockIdx.x*256 + threadIdx.x;   // 6912
  int cell = a/3, k = a%3;
  const float* rc = rpn + cell*18;
  float l0 = rc[2*k], l1 = rc[2*k+1];
  float m  = fmaxf(l0,l1);
  float e0 = expf(l0-m), e1 = expf(l1-m);
  float s  = e0 + e1;
  float p0 = e0/s, p1 = e1/s;
  probs[a*2+0] = p0; probs[a*2+1] = p1;
  float4 an = ((const float4*)anchors)[a];
  float r0 = rc[6+4*k+0], r1 = rc[6+4*k+1], r2 = rc[6+4*k+2], r3 = rc[6+4*k+3];
  float cxa = an.x + an.z*0.5f, cya = an.y + an.w*0.5f;
  float cx = r0*an.z + cxa, cy = r1*an.w + cya;
  float w  = an.z*expf(r2),  hh = an.w*expf(r3);
  float bx = cx - w*0.5f, by = cy - hh*0.5f;
  float x1 = fminf(fmaxf(bx,      0.0f), IMGF);
  float y1 = fminf(fmaxf(by,      0.0f), IMGF);
  float x2 = fminf(fmaxf(bx + w,  0.0f), IMGF);
  float y2 = fminf(fmaxf(by + hh, 0.0f), IMGF);
  float4 bo; bo.x = x1; bo.y = y1; bo.z = x2 - x1; bo.w = y2 - y1;
  ((float4*)boxes)[a] = bo;
  // descending score, ties -> lower index first (stable argsort semantics)
  keys[a] = ((ull)__float_as_uint(p1) << 32) | (unsigned)(NA-1-a);
}

// ---------------- K3a: partial ranks: part[jb][i] = #{j in tile jb : key[j] > key[i]} ----------------
__global__ __launch_bounds__(256) void rank_part(const ull* __restrict__ keys,
                                                 int* __restrict__ part){
  __shared__ ull lk[256];
  int t = threadIdx.x;
  int ib = blockIdx.x, jb = blockIdx.y;
  lk[t] = keys[jb*256 + t];
  int i = ib*256 + t;
  ull ki = keys[i];
  __syncthreads();
  int cnt = 0;
  #pragma unroll 16
  for (int j=0;j<256;++j) cnt += (lk[j] > ki) ? 1 : 0;
  part[jb*NA + i] = cnt;
}

// ---------------- K3b: sum partials -> rank, scatter ord + sorted boxes ----------------
__global__ __launch_bounds__(256) void rank_scatter(const int* __restrict__ part,
    const float* __restrict__ boxes, int* __restrict__ ord, float* __restrict__ sboxes){
  int i = blockIdx.x*256 + threadIdx.x;
  int r = 0;
  #pragma unroll
  for (int jb=0;jb<27;++jb) r += part[jb*NA + i];
  ord[r] = i;
  ((float4*)sboxes)[r] = ((const float4*)boxes)[i];
}

// ---------------- K4: IoU suppression bitmask (transposed layout) ----------------
// maskT[w*NA + i] : bit jj set iff IoU(box_i, box_{w*64+jj}) > 0.3
// Only read for (i>>6) <= w (diag blocks + phase-B rows from earlier chunks):
// skip the strictly-lower triangle -> ~2x less work.
__global__ __launch_bounds__(256) void iou_mask(const float* __restrict__ sboxes,
                                                ull* __restrict__ maskT){
  int gid = blockIdx.x*256 + threadIdx.x;  // 6912*108 threads
  int i = gid % NA;
  int w = gid / NA;
  if ((i >> 6) > w) return;                 // never consumed
  float4 bi = ((const float4*)sboxes)[i];
  float x1i = bi.x, y1i = bi.y;
  float x2i = bi.x + bi.z, y2i = bi.y + bi.w;
  float ai  = (x2i - x1i) * (y2i - y1i);
  const float4* bj4 = (const float4*)sboxes + w*64;
  ull bits = 0;
  #pragma unroll 8
  for (int jj=0;jj<64;++jj){
    float4 bj = bj4[jj];                      // uniform across wave -> broadcast
    float x1j = bj.x, y1j = bj.y;
    float x2j = bj.x + bj.z, y2j = bj.y + bj.w;
    float aj  = (x2j - x1j) * (y2j - y1j);
    float iw = fmaxf(fminf(x2i,x2j) - fmaxf(x1i,x1j), 0.0f);
    float ih = fmaxf(fminf(y2i,y2j) - fmaxf(y1i,y1j), 0.0f);
    float inter = iw*ih;
    float den = ai + aj - inter + 1e-8f;
    if (inter > 0.3f*den) bits |= (1ull<<jj);
  }
  maskT[(size_t)w*NA + i] = bits;
}

// ---------------- K5: fused NMS (block 0) + W_fc1 transpose/cvt (blocks 1..2304) ----------------
// Round-3 proven chunk structure (2 barriers, fully-parallel unrolled phase B,
// plain per-word writes) + diag double-buffer prefetch + PARALLEL fill path.
__global__ __launch_bounds__(256) void nms_wcvt(const ull* __restrict__ maskT,
    const int* __restrict__ ord, const float* __restrict__ sboxes,
    const float* __restrict__ probs, const float* __restrict__ Wfc1,
    ushort* __restrict__ Wt, float* __restrict__ out, float* __restrict__ selb){
  if (blockIdx.x != 0){
    // ---- wcvt: transpose W_fc1 [KFC][NHID] -> Wt [NHID][KFC], f32->bf16 ----
    __shared__ float tile[32][33];
    int bid = blockIdx.x - 1;
    int bx = bid & 31;          // n-tile (32 cols of W), 32
    int by = bid >> 5;          // k-tile (32 rows of W), 72
    int tx = threadIdx.x & 31, ty = threadIdx.x >> 5;
    #pragma unroll
    for (int it=0; it<4; ++it)
      tile[ty + 8*it][tx] = Wfc1[(size_t)(by*32 + ty + 8*it)*NHID + bx*32 + tx];
    __syncthreads();
    #pragma unroll
    for (int it=0; it<4; ++it){
      __hip_bfloat16 b = __float2bfloat16(tile[tx][ty + 8*it]);
      Wt[(size_t)(bx*32 + ty + 8*it)*KFC + by*32 + tx] = *(ushort*)&b;
    }
    return;
  }

  __shared__ ull remv[NW];
  __shared__ ull keepw[NW];
  __shared__ ull diag_sh[2][64];
  __shared__ ull kb_sh;
  __shared__ int selpos[RPOST];
  __shared__ int base_sh[NW];
  __shared__ int cnt_sh, done_sh;
  int t = threadIdx.x;
  if (t < NW){ remv[t] = 0ull; keepw[t] = 0ull; }
  if (t == 0){ cnt_sh = 0; done_sh = 0; }
  if (t < 64) diag_sh[0][t] = maskT[t];      // diag rows of chunk 0
  __syncthreads();

  for (int c = 0; c < NW; ++c){
    // prefetch next chunk's diag rows (independent of scan; waited before store)
    ull dreg = 0;
    if (t < 64 && c+1 < NW) dreg = maskT[(size_t)(c+1)*NA + (size_t)(c+1)*64 + t];

    if (t < 64){
      // phase A: greedy ffsll scan over kept bits (serial, LDS broadcast)
      const ull* dg = diag_sh[c & 1];
      ull w = remv[c];
      ull kb = 0;
      ull avail = ~w;
      while (avail){
        int b = __ffsll(avail) - 1;
        kb |= 1ull << b;
        w |= dg[b];
        avail &= ~w;
      }
      int cnt0 = cnt_sh;
      ull below = kb & ((1ull << t) - 1ull);
      int myrank = cnt0 + __popcll(below);
      if (((kb >> t) & 1ull) && myrank < RPOST) selpos[myrank] = c*64 + t;
      if (t == 0){
        kb_sh = kb;
        keepw[c] = kb;
        int nc = cnt0 + __popcll(kb);
        if (nc >= RPOST){ nc = RPOST; done_sh = 1; }
        cnt_sh = nc;
      }
    }
    __syncthreads();
    if (done_sh) break;                  // top-512 complete: uniform exit
    // phase B: OR kept rows into future remv words (one word per thread, no atomics)
    {
      ull kb = kb_sh;
      int wp = c + 1 + t;
      if (wp < NW && kb){
        ull acc = remv[wp];
        const ull* col = maskT + (size_t)wp*NA + (size_t)c*64;   // 64 contiguous qwords
        #pragma unroll
        for (int b=0;b<64;++b)
          acc |= (0ull - ((kb >> b) & 1ull)) & col[b];
        remv[wp] = acc;
      }
    }
    if (t < 64 && c+1 < NW) diag_sh[(c+1) & 1][t] = dreg;
    __syncthreads();
  }
  __syncthreads();
  // parallel fill path (<512 kept after full scan): suppressed positions, ascending
  int cnt0 = cnt_sh;
  if (cnt0 < RPOST){
    if (t < NW){
      int s = 0;
      for (int w2=0; w2<t; ++w2) s += __popcll(~keepw[w2]);
      base_sh[t] = s;
    }
    __syncthreads();
    for (int p = t; p < NA; p += 256){
      int w2 = p >> 6, b = p & 63;
      ull kw = keepw[w2];
      if (!((kw >> b) & 1ull)){
        int rank = cnt0 + base_sh[w2] + __popcll(~kw & ((1ull << b) - 1ull));
        if (rank < RPOST) selpos[rank] = p;
      }
    }
  }
  __syncthreads();
  for (int s=t; s<RPOST; s+=256){
    int pos = selpos[s];
    int orig = ord[pos];
    float4 b = ((const float4*)sboxes)[pos];
    out[s*10+0] = probs[orig*2+0];
    out[s*10+1] = probs[orig*2+1];
    out[s*10+2] = b.x; out[s*10+3] = b.y; out[s*10+4] = b.z; out[s*10+5] = b.w;
    ((float4*)selb)[s] = b;
  }
}

// ---------------- K7: ROIAlign (block = box, thread = channel) -> bf16 pooled ----------------
__global__ __launch_bounds__(256) void roialign(const float* __restrict__ feat,
    const float* __restrict__ selb, __hip_bfloat16* __restrict__ pooled){
  int r = blockIdx.x, c = threadIdx.x;
  float4 b = ((const float4*)selb)[r];
  int x0[6], x1[6], y0[6], y1[6];
  float wx[6], wy[6];
  #pragma unroll
  for (int s=0;s<6;++s){
    float off = ((float)s + 0.5f) / 6.0f;
    float fx = (b.x + off*b.z) / 32.0f - 0.5f;
    fx = fminf(fmaxf(fx, 0.0f), 47.0f);
    int xx0 = (int)floorf(fx);
    x0[s] = xx0; x1[s] = min(xx0+1, 47); wx[s] = fx - (float)xx0;
    float fy = (b.y + off*b.w) / 32.0f - 0.5f;
    fy = fminf(fmaxf(fy, 0.0f), 47.0f);
    int yy0 = (int)floorf(fy);
    y0[s] = yy0; y1[s] = min(yy0+1, 47); wy[s] = fy - (float)yy0;
  }
  #pragma unroll
  for (int ty=0;ty<3;++ty){
    #pragma unroll
    for (int tx=0;tx<3;++tx){
      float sum = 0.0f;
      #pragma unroll
      for (int py=0;py<2;++py){
        #pragma unroll
        for (int px=0;px<2;++px){
          int sy = ty*2+py, sx = tx*2+px;
          float wxx = wx[sx], wyy = wy[sy];
          float v00 = feat[(y0[sy]*MGRID + x0[sx])*CCH + c];
          float v01 = feat[(y0[sy]*MGRID + x1[sx])*CCH + c];
          float v10 = feat[(y1[sy]*MGRID + x0[sx])*CCH + c];
          float v11 = feat[(y1[sy]*MGRID + x1[sx])*CCH + c];
          sum += v00*(1.0f-wyy)*(1.0f-wxx) + v01*(1.0f-wyy)*wxx
               + v10*wyy*(1.0f-wxx)        + v11*wyy*wxx;
        }
      }
      pooled[((r*9) + ty*3 + tx)*CCH + c] = __float2bfloat16(sum * 0.25f);
    }
  }
}

// ---------------- K8: FC1 bf16 MFMA, 2-way K-split ----------------
// grid (16,8,2): z selects K half [z*1152,(z+1)*1152). Partial (bias in z=0, NO relu)
// written to Hp + z*512*1024. fc2 sums the two partials and applies relu.
__global__ __launch_bounds__(256) void fc1_mfma(const ushort* __restrict__ A,
    const ushort* __restrict__ Bt, const float* __restrict__ bias,
    float* __restrict__ Hp){
  __shared__ ushort As[4096];   // 64 rows x 64 k bf16, XOR-swizzled 16B chunks
  __shared__ ushort Bs[4096];
  const int t = threadIdx.x;
  const int bn = blockIdx.x, bm = blockIdx.y, bz = blockIdx.z;
  const int wv = t >> 6, lane = t & 63;
  const int wm = (wv >> 1) * 32, wn = (wv & 1) * 32;

  // staging: 16B chunk s in {t, t+256}; row = s>>3, kchunk = s&7
  const int r0 = t >> 3, kc = t & 7;
  const int r1 = r0 + 32;
  const int kbase = bz * 144;   // 1152 k * 2B / 16B
  const float4* gA0 = (const float4*)A  + (size_t)(bm*64 + r0)*288 + kbase + kc;
  const float4* gA1 = (const float4*)A  + (size_t)(bm*64 + r1)*288 + kbase + kc;
  const float4* gB0 = (const float4*)Bt + (size_t)(bn*64 + r0)*288 + kbase + kc;
  const float4* gB1 = (const float4*)Bt + (size_t)(bn*64 + r1)*288 + kbase + kc;
  float4* sA0 = (float4*)As + ((r0<<3) | (kc ^ (r0&7)));
  float4* sA1 = (float4*)As + ((r1<<3) | (kc ^ (r1&7)));
  float4* sB0 = (float4*)Bs + ((r0<<3) | (kc ^ (r0&7)));
  float4* sB1 = (float4*)Bs + ((r1<<3) | (kc ^ (r1&7)));

  const int fr = lane & 15, fkg = lane >> 4;
  const int arow0 = wm + fr,      arow1 = wm + 16 + fr;
  const int brow0 = wn + fr,      brow1 = wn + 16 + fr;

  f32x4 acc00{}, acc01{}, acc10{}, acc11{};

  const int KT = 18;            // 1152 / 64
  float4 pa0 = gA0[0], pa1 = gA1[0], pb0 = gB0[0], pb1 = gB1[0];
  for (int kt = 0; kt < KT; ++kt){
    __syncthreads();                          // previous compute done; LDS writable
    *sA0 = pa0; *sA1 = pa1; *sB0 = pb0; *sB1 = pb1;
    if (kt + 1 < KT){                         // T14: issue next tile's loads early
      pa0 = gA0[(kt+1)*8]; pa1 = gA1[(kt+1)*8];
      pb0 = gB0[(kt+1)*8]; pb1 = gB1[(kt+1)*8];
    }
    __syncthreads();                          // LDS tile ready
    #pragma unroll
    for (int kk2 = 0; kk2 < 2; ++kk2){
      int kidx = fkg + kk2*4;
      short8v a0 = *(const short8v*)(As + ((((arow0<<3) | (kidx ^ (arow0&7)))) << 3));
      short8v a1 = *(const short8v*)(As + ((((arow1<<3) | (kidx ^ (arow1&7)))) << 3));
      short8v b0 = *(const short8v*)(Bs + ((((brow0<<3) | (kidx ^ (brow0&7)))) << 3));
      short8v b1 = *(const short8v*)(Bs + ((((brow1<<3) | (kidx ^ (brow1&7)))) << 3));
      acc00 = __builtin_amdgcn_mfma_f32_16x16x32_bf16(a0, b0, acc00, 0, 0, 0);
      acc01 = __builtin_amdgcn_mfma_f32_16x16x32_bf16(a0, b1, acc01, 0, 0, 0);
      acc10 = __builtin_amdgcn_mfma_f32_16x16x32_bf16(a1, b0, acc10, 0, 0, 0);
      acc11 = __builtin_amdgcn_mfma_f32_16x16x32_bf16(a1, b1, acc11, 0, 0, 0);
    }
  }
  // epilogue: C/D layout col=lane&15, row=(lane>>4)*4+reg  [m89/m91 verified]
  float* H = Hp + (size_t)bz * 512 * NHID;
  const int orow = bm*64 + wm + (lane>>4)*4;
  const int ocol = bn*64 + wn + (lane&15);
  #pragma unroll
  for (int i=0;i<2;++i){
    #pragma unroll
    for (int j=0;j<2;++j){
      f32x4 a = (i==0) ? ((j==0)?acc00:acc01) : ((j==0)?acc10:acc11);
      #pragma unroll
      for (int reg=0;reg<4;++reg){
        int row = orow + i*16 + reg;
        int col = ocol + j*16;
        float v = a[reg] + (bz == 0 ? bias[col] : 0.0f);
        H[(size_t)row*NHID + col] = v;        // relu deferred to fc2
      }
    }
  }
}

// ---------------- K9: FC2 (sums K-split partials + relu) + unparameterize ----------------
__global__ __launch_bounds__(64) void fc2(const float* __restrict__ h0,
    const float* __restrict__ h1, const float* __restrict__ W2,
    const float* __restrict__ b2, const float* __restrict__ selb,
    float* __restrict__ out){
  int r = blockIdx.x, lane = threadIdx.x;
  float a0=0,a1=0,a2=0,a3=0;
  #pragma unroll 4
  for (int it=0; it<16; ++it){
    int k = it*64 + lane;
    float hv = fmaxf(h0[(size_t)r*NHID + k] + h1[(size_t)r*NHID + k], 0.0f);
    float4 w = ((const float4*)W2)[k];
    a0 += hv*w.x; a1 += hv*w.y; a2 += hv*w.z; a3 += hv*w.w;
  }
  #pragma unroll
  for (int off=32; off>0; off>>=1){
    a0 += __shfl_down(a0, off);
    a1 += __shfl_down(a1, off);
    a2 += __shfl_down(a2, off);
    a3 += __shfl_down(a3, off);
  }
  if (lane == 0){
    float4 b = ((const float4*)selb)[r];
    float r0 = a0 + b2[0], r1 = a1 + b2[1], r2 = a2 + b2[2], r3 = a3 + b2[3];
    float cxa = b.x + b.z*0.5f, cya = b.y + b.w*0.5f;
    float cx = r0*b.z + cxa, cy = r1*b.w + cya;
    float w  = b.z*expf(r2),  hh = b.w*expf(r3);
    out[r*10+6] = cx - w*0.5f;
    out[r*10+7] = cy - hh*0.5f;
    out[r*10+8] = w;
    out[r*10+9] = hh;
  }
}

extern "C" void kernel_launch(void* const* d_in, const int* in_sizes, int n_in,
                              void* d_out, int out_size, void* d_ws, size_t ws_size,
                              hipStream_t stream) {
  const float* feat    = (const float*)d_in[0];
  const float* anchors = (const float*)d_in[1];
  const float* Wobj    = (const float*)d_in[2];
  const float* bobj    = (const float*)d_in[3];
  const float* Wreg    = (const float*)d_in[4];
  const float* breg    = (const float*)d_in[5];
  const float* Wfc1    = (const float*)d_in[6];
  const float* bfc1    = (const float*)d_in[7];
  const float* Wfc2    = (const float*)d_in[8];
  const float* bfc2    = (const float*)d_in[9];
  float* out = (float*)d_out;
  char* ws = (char*)d_ws;

  float* rpn    = (float*)(ws + 0);          // 165888
  float* probs  = (float*)(ws + 165888);     // 55296
  float* boxes  = (float*)(ws + 221184);     // 110592
  ull*   keys   = (ull*)  (ws + 331776);     // 55296
  int*   ord    = (int*)  (ws + 387072);     // 27648
  float* sboxes = (float*)(ws + 414720);     // 110592
  int*   part   = (int*)  (ws + 525312);     // 746496 (dead after rank_scatter)
  ull*   maskT  = (ull*)  (ws + 1271808);    // 5971968 (live through nms)
  float* selb   = (float*)(ws + 7243776);    // 8192
  __hip_bfloat16* pooled = (__hip_bfloat16*)(ws + 7251968); // 2359296
  float* h      = (float*)(ws + 9611264);    // 2x 2097152 = 4194304 (K-split partials)
  ushort* Wt    = (ushort*)(ws + 13805568);  // 4718592 (concurrent with maskT; end 18524160)

  float* h0 = h;
  float* h1 = h + 512*NHID;

  hipLaunchKernelGGL(rpn_head,     dim3(162),     dim3(256), 0, stream, feat, Wobj, bobj, Wreg, breg, rpn);
  hipLaunchKernelGGL(anchor_prep,  dim3(27),      dim3(256), 0, stream, rpn, anchors, probs, boxes, keys);
  hipLaunchKernelGGL(rank_part,    dim3(27,27),   dim3(256), 0, stream, keys, part);
  hipLaunchKernelGGL(rank_scatter, dim3(27),      dim3(256), 0, stream, part, boxes, ord, sboxes);
  hipLaunchKernelGGL(iou_mask,     dim3(2916),    dim3(256), 0, stream, sboxes, maskT);
  hipLaunchKernelGGL(nms_wcvt,     dim3(2305),    dim3(256), 0, stream, maskT, ord, sboxes, probs, Wfc1, Wt, out, selb);
  hipLaunchKernelGGL(roialign,     dim3(512),     dim3(256), 0, stream, feat, selb, pooled);
  hipLaunchKernelGGL(fc1_mfma,     dim3(16,8,2),  dim3(256), 0, stream, (const ushort*)pooled, Wt, bfc1, h);
  hipLaunchKernelGGL(fc2,          dim3(512),     dim3(64),  0, stream, h0, h1, Wfc2, bfc2, selb, out);
}

// Round 7
// 92.250 us; speedup vs baseline: 1.6146x; 1.3323x over previous
//
#include <hip/hip_runtime.h>
#include <hip/hip_bf16.h>

typedef unsigned long long ull;

#define MGRID 48
#define CCH   256
#define NCELL 2304      // 48*48
#define NA    6912      // anchors
#define NW    108       // NA/64
#define NHID  1024
#define KFC   2304      // 9*256
#define RPOST 512
#define IMGF  1536.0f

typedef __attribute__((ext_vector_type(8))) short short8v;  // 8 bf16
typedef __attribute__((ext_vector_type(4))) float f32x4;

// ---------------- K1: RPN head: per (cell, o) dot product ----------------
__global__ __launch_bounds__(256) void rpn_head(const float* __restrict__ feat,
    const float* __restrict__ Wobj, const float* __restrict__ bobj,
    const float* __restrict__ Wreg, const float* __restrict__ breg,
    float* __restrict__ rpn){
  int g = blockIdx.x*256 + threadIdx.x;   // 2304*18 = 41472 threads
  int cell = g / 18, o = g % 18;
  const float* x = feat + cell*CCH;
  const float* W; int stride; float acc;
  if (o < 6){ W = Wobj + o; stride = 6;  acc = bobj[o];   }
  else      { W = Wreg + (o-6); stride = 12; acc = breg[o-6]; }
  #pragma unroll 8
  for (int c=0;c<CCH;++c) acc += x[c]*W[c*stride];
  rpn[cell*18 + o] = acc;
}

// ---------------- K2: per-anchor softmax, box decode, sort key ----------------
__global__ __launch_bounds__(256) void anchor_prep(const float* __restrict__ rpn,
    const float* __restrict__ anchors, float* __restrict__ probs,
    float* __restrict__ boxes, ull* __restrict__ keys){
  int a = blockIdx.x*256 + threadIdx.x;   // 6912
  int cell = a/3, k = a%3;
  const float* rc = rpn + cell*18;
  float l0 = rc[2*k], l1 = rc[2*k+1];
  float m  = fmaxf(l0,l1);
  float e0 = expf(l0-m), e1 = expf(l1-m);
  float s  = e0 + e1;
  float p0 = e0/s, p1 = e1/s;
  probs[a*2+0] = p0; probs[a*2+1] = p1;
  float4 an = ((const float4*)anchors)[a];
  float r0 = rc[6+4*k+0], r1 = rc[6+4*k+1], r2 = rc[6+4*k+2], r3 = rc[6+4*k+3];
  float cxa = an.x + an.z*0.5f, cya = an.y + an.w*0.5f;
  float cx = r0*an.z + cxa, cy = r1*an.w + cya;
  float w  = an.z*expf(r2),  hh = an.w*expf(r3);
  float bx = cx - w*0.5f, by = cy - hh*0.5f;
  float x1 = fminf(fmaxf(bx,      0.0f), IMGF);
  float y1 = fminf(fmaxf(by,      0.0f), IMGF);
  float x2 = fminf(fmaxf(bx + w,  0.0f), IMGF);
  float y2 = fminf(fmaxf(by + hh, 0.0f), IMGF);
  float4 bo; bo.x = x1; bo.y = y1; bo.z = x2 - x1; bo.w = y2 - y1;
  ((float4*)boxes)[a] = bo;
  // descending score, ties -> lower index first (stable argsort semantics)
  keys[a] = ((ull)__float_as_uint(p1) << 32) | (unsigned)(NA-1-a);
}

// ---------------- K3a: partial ranks: part[jb][i] = #{j in tile jb : key[j] > key[i]} ----------------
__global__ __launch_bounds__(256) void rank_part(const ull* __restrict__ keys,
                                                 int* __restrict__ part){
  __shared__ ull lk[256];
  int t = threadIdx.x;
  int ib = blockIdx.x, jb = blockIdx.y;
  lk[t] = keys[jb*256 + t];
  int i = ib*256 + t;
  ull ki = keys[i];
  __syncthreads();
  int cnt = 0;
  #pragma unroll 16
  for (int j=0;j<256;++j) cnt += (lk[j] > ki) ? 1 : 0;
  part[jb*NA + i] = cnt;
}

// ---------------- K3b: sum partials -> rank, scatter ord + sorted boxes ----------------
__global__ __launch_bounds__(256) void rank_scatter(const int* __restrict__ part,
    const float* __restrict__ boxes, int* __restrict__ ord, float* __restrict__ sboxes){
  int i = blockIdx.x*256 + threadIdx.x;
  int r = 0;
  #pragma unroll
  for (int jb=0;jb<27;++jb) r += part[jb*NA + i];
  ord[r] = i;
  ((float4*)sboxes)[r] = ((const float4*)boxes)[i];
}

// ---------------- K4: IoU suppression bitmask (transposed layout) ----------------
// maskT[w*NA + i] : bit jj set iff IoU(box_i, box_{w*64+jj}) > 0.3
// Consumed only for (i>>6) <= w+1 (diag, first SUBdiagonal band for the srow
// urgent trick, upper triangle for phase B): skip the rest (~2x less work).
__global__ __launch_bounds__(256) void iou_mask(const float* __restrict__ sboxes,
                                                ull* __restrict__ maskT){
  int gid = blockIdx.x*256 + threadIdx.x;  // 6912*108 threads
  int i = gid % NA;
  int w = gid / NA;
  if ((i >> 6) > w + 1) return;             // never consumed
  float4 bi = ((const float4*)sboxes)[i];
  float x1i = bi.x, y1i = bi.y;
  float x2i = bi.x + bi.z, y2i = bi.y + bi.w;
  float ai  = (x2i - x1i) * (y2i - y1i);
  const float4* bj4 = (const float4*)sboxes + w*64;
  ull bits = 0;
  #pragma unroll 8
  for (int jj=0;jj<64;++jj){
    float4 bj = bj4[jj];                      // uniform across wave -> broadcast
    float x1j = bj.x, y1j = bj.y;
    float x2j = bj.x + bj.z, y2j = bj.y + bj.w;
    float aj  = (x2j - x1j) * (y2j - y1j);
    float iw = fmaxf(fminf(x2i,x2j) - fmaxf(x1i,x1j), 0.0f);
    float ih = fmaxf(fminf(y2i,y2j) - fmaxf(y1i,y1j), 0.0f);
    float inter = iw*ih;
    float den = ai + aj - inter + 1e-8f;
    if (inter > 0.3f*den) bits |= (1ull<<jj);
  }
  maskT[(size_t)w*NA + i] = bits;
}

// ---------------- K5: fused NMS (block 0) + W_fc1 transpose/cvt (blocks 1..2304) ----------------
// Per chunk c, ONE barrier:
//  wave0:  ballot-fixpoint keep resolve, 100% registers (lane t holds its OWN diag
//          row; IoU symmetry => sup = dg & below(t)). Cross-chunk c-1 suppression
//          via srow = maskT[(c-1)*NA + c*64 + t] & kb_prev (prefetched; no shuffles).
//  waves1-3: deferred phase B: kb(c-1) -> remv[c+1..] via 64 UNROLLED independent
//          loads (overlaps wave0's fixpoint; one thread per word, no atomics).
// Fill path (<512 kept after full scan) parallel via per-word popcount prefix.
__global__ __launch_bounds__(256) void nms_wcvt(const ull* __restrict__ maskT,
    const int* __restrict__ ord, const float* __restrict__ sboxes,
    const float* __restrict__ probs, const float* __restrict__ Wfc1,
    ushort* __restrict__ Wt, float* __restrict__ out, float* __restrict__ selb){
  if (blockIdx.x != 0){
    // ---- wcvt: transpose W_fc1 [KFC][NHID] -> Wt [NHID][KFC], f32->bf16 ----
    __shared__ float tile[32][33];
    int bid = blockIdx.x - 1;
    int bx = bid & 31;          // n-tile (32 cols of W), 32
    int by = bid >> 5;          // k-tile (32 rows of W), 72
    int tx = threadIdx.x & 31, ty = threadIdx.x >> 5;
    #pragma unroll
    for (int it=0; it<4; ++it)
      tile[ty + 8*it][tx] = Wfc1[(size_t)(by*32 + ty + 8*it)*NHID + bx*32 + tx];
    __syncthreads();
    #pragma unroll
    for (int it=0; it<4; ++it){
      __hip_bfloat16 b = __float2bfloat16(tile[tx][ty + 8*it]);
      Wt[(size_t)(bx*32 + ty + 8*it)*KFC + by*32 + tx] = *(ushort*)&b;
    }
    return;
  }

  __shared__ ull remv[NW];
  __shared__ ull keepw[NW];
  __shared__ ull kb_sh[2];
  __shared__ int selpos[RPOST];
  __shared__ int base_sh[NW];
  __shared__ int cnt_sh, done_sh;
  int t = threadIdx.x;
  if (t < NW){ remv[t] = 0ull; keepw[t] = 0ull; }
  if (t == 0){ cnt_sh = 0; done_sh = 0; kb_sh[0] = 0ull; kb_sh[1] = 0ull; }
  __syncthreads();

  ull dg_cur = 0, srow_cur = 0, kb_prev = 0;
  if (t < 64) dg_cur = maskT[t];            // chunk 0 diag row (own lane's row)

  for (int c = 0; c < NW; ++c){
    if (t < 64){
      // prefetch chunk c+1's diag row + suppressor-row vs chunk c (coalesced)
      ull dg_nxt = 0, srow_nxt = 0;
      if (c+1 < NW){
        dg_nxt   = maskT[(size_t)(c+1)*NA + (size_t)(c+1)*64 + t];
        srow_nxt = maskT[(size_t)c*NA + (size_t)(c+1)*64 + t];
      }
      // phase A: register-only ballot fixpoint
      ull w0 = remv[c];
      bool dec  = ((w0 >> t) & 1ull) || ((srow_cur & kb_prev) != 0ull);
      bool kept = false;
      ull sup = dg_cur & ((1ull << t) - 1ull);   // earlier in-chunk suppressors
      for (;;){
        ull K = __ballot(kept);
        ull D = __ballot(dec);
        if (D == ~0ull) break;            // lowest undecided lane decides each round
        if (!dec){
          if (sup & K)                 { dec = true; }
          else if ((sup & ~D) == 0ull) { dec = true; kept = true; }
        }
      }
      ull kb = __ballot(kept);
      int cnt0 = cnt_sh;
      ull below = kb & ((1ull << t) - 1ull);
      int myrank = cnt0 + __popcll(below);
      if (kept && myrank < RPOST) selpos[myrank] = c*64 + t;
      if (t == 0){
        kb_sh[c & 1] = kb;
        keepw[c] = kb;
        int nc = cnt0 + __popcll(kb);
        if (nc >= RPOST){ nc = RPOST; done_sh = 1; }
        cnt_sh = nc;
      }
      kb_prev = kb; dg_cur = dg_nxt; srow_cur = srow_nxt;
    } else {
      // deferred phase B: kb(c-1) -> remv[c+1 ..] (one word/thread, unrolled)
      int u = t - 64;
      int wp = c + 1 + u;
      if (c >= 1 && wp < NW){
        ull kbp = kb_sh[(c-1) & 1];
        if (kbp){
          const ull* row = maskT + (size_t)wp*NA + (size_t)(c-1)*64;
          ull acc = remv[wp];
          #pragma unroll
          for (int b=0;b<64;++b)
            acc |= (0ull - ((kbp >> b) & 1ull)) & row[b];
          remv[wp] = acc;
        }
      }
    }
    __syncthreads();
    if (done_sh) break;                   // top-512 complete: uniform exit
  }
  __syncthreads();
  // parallel fill path (<512 kept after full scan): suppressed positions, ascending
  int cnt0 = cnt_sh;
  if (cnt0 < RPOST){
    if (t < NW){
      int s = 0;
      for (int w2=0; w2<t; ++w2) s += __popcll(~keepw[w2]);
      base_sh[t] = s;
    }
    __syncthreads();
    for (int p = t; p < NA; p += 256){
      int w2 = p >> 6, b = p & 63;
      ull kw = keepw[w2];
      if (!((kw >> b) & 1ull)){
        int rank = cnt0 + base_sh[w2] + __popcll(~kw & ((1ull << b) - 1ull));
        if (rank < RPOST) selpos[rank] = p;
      }
    }
  }
  __syncthreads();
  for (int s=t; s<RPOST; s+=256){
    int pos = selpos[s];
    int orig = ord[pos];
    float4 b = ((const float4*)sboxes)[pos];
    out[s*10+0] = probs[orig*2+0];
    out[s*10+1] = probs[orig*2+1];
    out[s*10+2] = b.x; out[s*10+3] = b.y; out[s*10+4] = b.z; out[s*10+5] = b.w;
    ((float4*)selb)[s] = b;
  }
}

// ---------------- K7: ROIAlign (block = box, thread = channel) -> bf16 pooled ----------------
__global__ __launch_bounds__(256) void roialign(const float* __restrict__ feat,
    const float* __restrict__ selb, __hip_bfloat16* __restrict__ pooled){
  int r = blockIdx.x, c = threadIdx.x;
  float4 b = ((const float4*)selb)[r];
  int x0[6], x1[6], y0[6], y1[6];
  float wx[6], wy[6];
  #pragma unroll
  for (int s=0;s<6;++s){
    float off = ((float)s + 0.5f) / 6.0f;
    float fx = (b.x + off*b.z) / 32.0f - 0.5f;
    fx = fminf(fmaxf(fx, 0.0f), 47.0f);
    int xx0 = (int)floorf(fx);
    x0[s] = xx0; x1[s] = min(xx0+1, 47); wx[s] = fx - (float)xx0;
    float fy = (b.y + off*b.w) / 32.0f - 0.5f;
    fy = fminf(fmaxf(fy, 0.0f), 47.0f);
    int yy0 = (int)floorf(fy);
    y0[s] = yy0; y1[s] = min(yy0+1, 47); wy[s] = fy - (float)yy0;
  }
  #pragma unroll
  for (int ty=0;ty<3;++ty){
    #pragma unroll
    for (int tx=0;tx<3;++tx){
      float sum = 0.0f;
      #pragma unroll
      for (int py=0;py<2;++py){
        #pragma unroll
        for (int px=0;px<2;++px){
          int sy = ty*2+py, sx = tx*2+px;
          float wxx = wx[sx], wyy = wy[sy];
          float v00 = feat[(y0[sy]*MGRID + x0[sx])*CCH + c];
          float v01 = feat[(y0[sy]*MGRID + x1[sx])*CCH + c];
          float v10 = feat[(y1[sy]*MGRID + x0[sx])*CCH + c];
          float v11 = feat[(y1[sy]*MGRID + x1[sx])*CCH + c];
          sum += v00*(1.0f-wyy)*(1.0f-wxx) + v01*(1.0f-wyy)*wxx
               + v10*wyy*(1.0f-wxx)        + v11*wyy*wxx;
        }
      }
      pooled[((r*9) + ty*3 + tx)*CCH + c] = __float2bfloat16(sum * 0.25f);
    }
  }
}

// ---------------- K8: FC1 bf16 MFMA, 2-way K-split ----------------
// grid (16,8,2): z selects K half [z*1152,(z+1)*1152). Partial (bias in z=0, NO relu)
// written to Hp + z*512*1024. fc2 sums the two partials and applies relu.
__global__ __launch_bounds__(256) void fc1_mfma(const ushort* __restrict__ A,
    const ushort* __restrict__ Bt, const float* __restrict__ bias,
    float* __restrict__ Hp){
  __shared__ ushort As[4096];   // 64 rows x 64 k bf16, XOR-swizzled 16B chunks
  __shared__ ushort Bs[4096];
  const int t = threadIdx.x;
  const int bn = blockIdx.x, bm = blockIdx.y, bz = blockIdx.z;
  const int wv = t >> 6, lane = t & 63;
  const int wm = (wv >> 1) * 32, wn = (wv & 1) * 32;

  // staging: 16B chunk s in {t, t+256}; row = s>>3, kchunk = s&7
  const int r0 = t >> 3, kc = t & 7;
  const int r1 = r0 + 32;
  const int kbase = bz * 144;   // 1152 k * 2B / 16B
  const float4* gA0 = (const float4*)A  + (size_t)(bm*64 + r0)*288 + kbase + kc;
  const float4* gA1 = (const float4*)A  + (size_t)(bm*64 + r1)*288 + kbase + kc;
  const float4* gB0 = (const float4*)Bt + (size_t)(bn*64 + r0)*288 + kbase + kc;
  const float4* gB1 = (const float4*)Bt + (size_t)(bn*64 + r1)*288 + kbase + kc;
  float4* sA0 = (float4*)As + ((r0<<3) | (kc ^ (r0&7)));
  float4* sA1 = (float4*)As + ((r1<<3) | (kc ^ (r1&7)));
  float4* sB0 = (float4*)Bs + ((r0<<3) | (kc ^ (r0&7)));
  float4* sB1 = (float4*)Bs + ((r1<<3) | (kc ^ (r1&7)));

  const int fr = lane & 15, fkg = lane >> 4;
  const int arow0 = wm + fr,      arow1 = wm + 16 + fr;
  const int brow0 = wn + fr,      brow1 = wn + 16 + fr;

  f32x4 acc00{}, acc01{}, acc10{}, acc11{};

  const int KT = 18;            // 1152 / 64
  float4 pa0 = gA0[0], pa1 = gA1[0], pb0 = gB0[0], pb1 = gB1[0];
  for (int kt = 0; kt < KT; ++kt){
    __syncthreads();                          // previous compute done; LDS writable
    *sA0 = pa0; *sA1 = pa1; *sB0 = pb0; *sB1 = pb1;
    if (kt + 1 < KT){                         // T14: issue next tile's loads early
      pa0 = gA0[(kt+1)*8]; pa1 = gA1[(kt+1)*8];
      pb0 = gB0[(kt+1)*8]; pb1 = gB1[(kt+1)*8];
    }
    __syncthreads();                          // LDS tile ready
    #pragma unroll
    for (int kk2 = 0; kk2 < 2; ++kk2){
      int kidx = fkg + kk2*4;
      short8v a0 = *(const short8v*)(As + ((((arow0<<3) | (kidx ^ (arow0&7)))) << 3));
      short8v a1 = *(const short8v*)(As + ((((arow1<<3) | (kidx ^ (arow1&7)))) << 3));
      short8v b0 = *(const short8v*)(Bs + ((((brow0<<3) | (kidx ^ (brow0&7)))) << 3));
      short8v b1 = *(const short8v*)(Bs + ((((brow1<<3) | (kidx ^ (brow1&7)))) << 3));
      acc00 = __builtin_amdgcn_mfma_f32_16x16x32_bf16(a0, b0, acc00, 0, 0, 0);
      acc01 = __builtin_amdgcn_mfma_f32_16x16x32_bf16(a0, b1, acc01, 0, 0, 0);
      acc10 = __builtin_amdgcn_mfma_f32_16x16x32_bf16(a1, b0, acc10, 0, 0, 0);
      acc11 = __builtin_amdgcn_mfma_f32_16x16x32_bf16(a1, b1, acc11, 0, 0, 0);
    }
  }
  // epilogue: C/D layout col=lane&15, row=(lane>>4)*4+reg  [m89/m91 verified]
  float* H = Hp + (size_t)bz * 512 * NHID;
  const int orow = bm*64 + wm + (lane>>4)*4;
  const int ocol = bn*64 + wn + (lane&15);
  #pragma unroll
  for (int i=0;i<2;++i){
    #pragma unroll
    for (int j=0;j<2;++j){
      f32x4 a = (i==0) ? ((j==0)?acc00:acc01) : ((j==0)?acc10:acc11);
      #pragma unroll
      for (int reg=0;reg<4;++reg){
        int row = orow + i*16 + reg;
        int col = ocol + j*16;
        float v = a[reg] + (bz == 0 ? bias[col] : 0.0f);
        H[(size_t)row*NHID + col] = v;        // relu deferred to fc2
      }
    }
  }
}

// ---------------- K9: FC2 (sums K-split partials + relu) + unparameterize ----------------
__global__ __launch_bounds__(64) void fc2(const float* __restrict__ h0,
    const float* __restrict__ h1, const float* __restrict__ W2,
    const float* __restrict__ b2, const float* __restrict__ selb,
    float* __restrict__ out){
  int r = blockIdx.x, lane = threadIdx.x;
  float a0=0,a1=0,a2=0,a3=0;
  #pragma unroll 4
  for (int it=0; it<16; ++it){
    int k = it*64 + lane;
    float hv = fmaxf(h0[(size_t)r*NHID + k] + h1[(size_t)r*NHID + k], 0.0f);
    float4 w = ((const float4*)W2)[k];
    a0 += hv*w.x; a1 += hv*w.y; a2 += hv*w.z; a3 += hv*w.w;
  }
  #pragma unroll
  for (int off=32; off>0; off>>=1){
    a0 += __shfl_down(a0, off);
    a1 += __shfl_down(a1, off);
    a2 += __shfl_down(a2, off);
    a3 += __shfl_down(a3, off);
  }
  if (lane == 0){
    float4 b = ((const float4*)selb)[r];
    float r0 = a0 + b2[0], r1 = a1 + b2[1], r2 = a2 + b2[2], r3 = a3 + b2[3];
    float cxa = b.x + b.z*0.5f, cya = b.y + b.w*0.5f;
    float cx = r0*b.z + cxa, cy = r1*b.w + cya;
    float w  = b.z*expf(r2),  hh = b.w*expf(r3);
    out[r*10+6] = cx - w*0.5f;
    out[r*10+7] = cy - hh*0.5f;
    out[r*10+8] = w;
    out[r*10+9] = hh;
  }
}

extern "C" void kernel_launch(void* const* d_in, const int* in_sizes, int n_in,
                              void* d_out, int out_size, void* d_ws, size_t ws_size,
                              hipStream_t stream) {
  const float* feat    = (const float*)d_in[0];
  const float* anchors = (const float*)d_in[1];
  const float* Wobj    = (const float*)d_in[2];
  const float* bobj    = (const float*)d_in[3];
  const float* Wreg    = (const float*)d_in[4];
  const float* breg    = (const float*)d_in[5];
  const float* Wfc1    = (const float*)d_in[6];
  const float* bfc1    = (const float*)d_in[7];
  const float* Wfc2    = (const float*)d_in[8];
  const float* bfc2    = (const float*)d_in[9];
  float* out = (float*)d_out;
  char* ws = (char*)d_ws;

  float* rpn    = (float*)(ws + 0);          // 165888
  float* probs  = (float*)(ws + 165888);     // 55296
  float* boxes  = (float*)(ws + 221184);     // 110592
  ull*   keys   = (ull*)  (ws + 331776);     // 55296
  int*   ord    = (int*)  (ws + 387072);     // 27648
  float* sboxes = (float*)(ws + 414720);     // 110592
  int*   part   = (int*)  (ws + 525312);     // 746496 (dead after rank_scatter)
  ull*   maskT  = (ull*)  (ws + 1271808);    // 5971968 (live through nms)
  float* selb   = (float*)(ws + 7243776);    // 8192
  __hip_bfloat16* pooled = (__hip_bfloat16*)(ws + 7251968); // 2359296
  float* h      = (float*)(ws + 9611264);    // 2x 2097152 = 4194304 (K-split partials)
  ushort* Wt    = (ushort*)(ws + 13805568);  // 4718592 (concurrent with maskT; end 18524160)

  float* h0 = h;
  float* h1 = h + 512*NHID;

  hipLaunchKernelGGL(rpn_head,     dim3(162),     dim3(256), 0, stream, feat, Wobj, bobj, Wreg, breg, rpn);
  hipLaunchKernelGGL(anchor_prep,  dim3(27),      dim3(256), 0, stream, rpn, anchors, probs, boxes, keys);
  hipLaunchKernelGGL(rank_part,    dim3(27,27),   dim3(256), 0, stream, keys, part);
  hipLaunchKernelGGL(rank_scatter, dim3(27),      dim3(256), 0, stream, part, boxes, ord, sboxes);
  hipLaunchKernelGGL(iou_mask,     dim3(2916),    dim3(256), 0, stream, sboxes, maskT);
  hipLaunchKernelGGL(nms_wcvt,     dim3(2305),    dim3(256), 0, stream, maskT, ord, sboxes, probs, Wfc1, Wt, out, selb);
  hipLaunchKernelGGL(roialign,     dim3(512),     dim3(256), 0, stream, feat, selb, pooled);
  hipLaunchKernelGGL(fc1_mfma,     dim3(16,8,2),  dim3(256), 0, stream, (const ushort*)pooled, Wt, bfc1, h);
  hipLaunchKernelGGL(fc2,          dim3(512),     dim3(64),  0, stream, h0, h1, Wfc2, bfc2, selb, out);
}

// Round 8
// 91.210 us; speedup vs baseline: 1.6330x; 1.0114x over previous
//
#include <hip/hip_runtime.h>
#include <hip/hip_bf16.h>

typedef unsigned long long ull;

#define MGRID 48
#define CCH   256
#define NCELL 2304      // 48*48
#define NA    6912      // anchors
#define NW    108       // NA/64
#define NHID  1024
#define KFC   2304      // 9*256
#define RPOST 512
#define IMGF  1536.0f

typedef __attribute__((ext_vector_type(8))) short short8v;  // 8 bf16
typedef __attribute__((ext_vector_type(4))) float f32x4;

// ---------------- K1: fused RPN head (blocks 0..161) + wcvt (blocks 162..2465) ----------------
// wcvt overlaps the front-end here (Wt not needed until fc1); keeps NMS uncontended.
__global__ __launch_bounds__(256) void rpn_wcvt(const float* __restrict__ feat,
    const float* __restrict__ Wobj, const float* __restrict__ bobj,
    const float* __restrict__ Wreg, const float* __restrict__ breg,
    float* __restrict__ rpn, const float* __restrict__ Wfc1,
    ushort* __restrict__ Wt){
  if (blockIdx.x >= 162){
    // ---- wcvt: transpose W_fc1 [KFC][NHID] -> Wt [NHID][KFC], f32->bf16 ----
    __shared__ float tile[32][33];
    int bid = blockIdx.x - 162;
    int bx = bid & 31;          // n-tile (32 cols of W), 32
    int by = bid >> 5;          // k-tile (32 rows of W), 72
    int tx = threadIdx.x & 31, ty = threadIdx.x >> 5;
    #pragma unroll
    for (int it=0; it<4; ++it)
      tile[ty + 8*it][tx] = Wfc1[(size_t)(by*32 + ty + 8*it)*NHID + bx*32 + tx];
    __syncthreads();
    #pragma unroll
    for (int it=0; it<4; ++it){
      __hip_bfloat16 b = __float2bfloat16(tile[tx][ty + 8*it]);
      Wt[(size_t)(bx*32 + ty + 8*it)*KFC + by*32 + tx] = *(ushort*)&b;
    }
    return;
  }
  int g = blockIdx.x*256 + threadIdx.x;   // 2304*18 = 41472 threads
  int cell = g / 18, o = g % 18;
  const float* W; int stride; float acc;
  if (o < 6){ W = Wobj + o; stride = 6;  acc = bobj[o];   }
  else      { W = Wreg + (o-6); stride = 12; acc = breg[o-6]; }
  // float4 x-loads; scalar adds in the SAME sequential c-order (FP rounding preserved)
  const float4* x4 = (const float4*)(feat + cell*CCH);
  #pragma unroll 4
  for (int c4=0;c4<CCH/4;++c4){
    float4 xv = x4[c4];
    acc += xv.x*W[(4*c4+0)*stride];
    acc += xv.y*W[(4*c4+1)*stride];
    acc += xv.z*W[(4*c4+2)*stride];
    acc += xv.w*W[(4*c4+3)*stride];
  }
  rpn[cell*18 + o] = acc;
}

// ---------------- K2: per-anchor softmax, box decode, sort key ----------------
__global__ __launch_bounds__(256) void anchor_prep(const float* __restrict__ rpn,
    const float* __restrict__ anchors, float* __restrict__ probs,
    float* __restrict__ boxes, ull* __restrict__ keys){
  int a = blockIdx.x*256 + threadIdx.x;   // 6912
  int cell = a/3, k = a%3;
  const float* rc = rpn + cell*18;
  float l0 = rc[2*k], l1 = rc[2*k+1];
  float m  = fmaxf(l0,l1);
  float e0 = expf(l0-m), e1 = expf(l1-m);
  float s  = e0 + e1;
  float p0 = e0/s, p1 = e1/s;
  probs[a*2+0] = p0; probs[a*2+1] = p1;
  float4 an = ((const float4*)anchors)[a];
  float r0 = rc[6+4*k+0], r1 = rc[6+4*k+1], r2 = rc[6+4*k+2], r3 = rc[6+4*k+3];
  float cxa = an.x + an.z*0.5f, cya = an.y + an.w*0.5f;
  float cx = r0*an.z + cxa, cy = r1*an.w + cya;
  float w  = an.z*expf(r2),  hh = an.w*expf(r3);
  float bx = cx - w*0.5f, by = cy - hh*0.5f;
  float x1 = fminf(fmaxf(bx,      0.0f), IMGF);
  float y1 = fminf(fmaxf(by,      0.0f), IMGF);
  float x2 = fminf(fmaxf(bx + w,  0.0f), IMGF);
  float y2 = fminf(fmaxf(by + hh, 0.0f), IMGF);
  float4 bo; bo.x = x1; bo.y = y1; bo.z = x2 - x1; bo.w = y2 - y1;
  ((float4*)boxes)[a] = bo;
  // descending score, ties -> lower index first (stable argsort semantics)
  keys[a] = ((ull)__float_as_uint(p1) << 32) | (unsigned)(NA-1-a);
}

// ---------------- K3a: partial ranks: part[jb][i] = #{j in tile jb : key[j] > key[i]} ----------------
__global__ __launch_bounds__(256) void rank_part(const ull* __restrict__ keys,
                                                 int* __restrict__ part){
  __shared__ ull lk[256];
  int t = threadIdx.x;
  int ib = blockIdx.x, jb = blockIdx.y;
  lk[t] = keys[jb*256 + t];
  int i = ib*256 + t;
  ull ki = keys[i];
  __syncthreads();
  int cnt = 0;
  #pragma unroll 16
  for (int j=0;j<256;++j) cnt += (lk[j] > ki) ? 1 : 0;
  part[jb*NA + i] = cnt;
}

// ---------------- K3b: sum partials -> rank, scatter ord + sorted boxes ----------------
__global__ __launch_bounds__(256) void rank_scatter(const int* __restrict__ part,
    const float* __restrict__ boxes, int* __restrict__ ord, float* __restrict__ sboxes){
  int i = blockIdx.x*256 + threadIdx.x;
  int r = 0;
  #pragma unroll
  for (int jb=0;jb<27;++jb) r += part[jb*NA + i];
  ord[r] = i;
  ((float4*)sboxes)[r] = ((const float4*)boxes)[i];
}

// ---------------- K4: IoU suppression bitmask, COMPACTED triangular grid ----------------
// maskT[w*NA + i], computed only where consumed: (i>>6) <= w+1.
// 64-thread group q -> (w, ib) via inverse triangle: G(w)=w(w+3)/2, q in [G(w),G(w+1)).
#define NQ 5993   // G(107)=5885 + 108 groups at w=107
__global__ __launch_bounds__(256) void iou_mask(const float* __restrict__ sboxes,
                                                ull* __restrict__ maskT){
  int g = blockIdx.x*256 + threadIdx.x;
  int q = g >> 6;
  if (q >= NQ) return;
  int w = (int)((sqrtf(8.0f*(float)q + 9.0f) - 3.0f) * 0.5f);
  if (w > 107) w = 107;
  while (w < 107 && (w+1)*(w+4)/2 <= q) ++w;
  while (w > 0 && w*(w+3)/2 > q) --w;
  int ib = q - w*(w+3)/2;
  int i = ib*64 + (g & 63);
  float4 bi = ((const float4*)sboxes)[i];
  float x1i = bi.x, y1i = bi.y;
  float x2i = bi.x + bi.z, y2i = bi.y + bi.w;
  float ai  = (x2i - x1i) * (y2i - y1i);
  const float4* bj4 = (const float4*)sboxes + w*64;
  ull bits = 0;
  #pragma unroll 8
  for (int jj=0;jj<64;++jj){
    float4 bj = bj4[jj];                      // uniform across wave -> broadcast
    float x1j = bj.x, y1j = bj.y;
    float x2j = bj.x + bj.z, y2j = bj.y + bj.w;
    float aj  = (x2j - x1j) * (y2j - y1j);
    float iw = fmaxf(fminf(x2i,x2j) - fmaxf(x1i,x1j), 0.0f);
    float ih = fmaxf(fminf(y2i,y2j) - fmaxf(y1i,y1j), 0.0f);
    float inter = iw*ih;
    float den = ai + aj - inter + 1e-8f;
    if (inter > 0.3f*den) bits |= (1ull<<jj);
  }
  maskT[(size_t)w*NA + i] = bits;
}

// ---------------- K5: NMS (single block, uncontended) ----------------
// Per chunk c, ONE barrier:
//  wave0:  ballot-fixpoint keep resolve, 100% registers (lane t holds its OWN diag
//          row; IoU symmetry => sup = dg & below(t)). Cross-chunk c-1 suppression
//          via srow = maskT[(c-1)*NA + c*64 + t] & kb_prev (prefetched; no shuffles).
//  waves1-3: deferred phase B: kb(c-1) -> remv[c+1..] via 64 UNROLLED independent
//          loads (overlaps wave0's fixpoint; one thread per word, no atomics).
// Fill path (<512 kept after full scan) parallel via per-word popcount prefix.
__global__ __launch_bounds__(256) void nms(const ull* __restrict__ maskT,
    const int* __restrict__ ord, const float* __restrict__ sboxes,
    const float* __restrict__ probs, float* __restrict__ out,
    float* __restrict__ selb){
  __shared__ ull remv[NW];
  __shared__ ull keepw[NW];
  __shared__ ull kb_sh[2];
  __shared__ int selpos[RPOST];
  __shared__ int base_sh[NW];
  __shared__ int cnt_sh, done_sh;
  int t = threadIdx.x;
  if (t < NW){ remv[t] = 0ull; keepw[t] = 0ull; }
  if (t == 0){ cnt_sh = 0; done_sh = 0; kb_sh[0] = 0ull; kb_sh[1] = 0ull; }
  __syncthreads();

  ull dg_cur = 0, srow_cur = 0, kb_prev = 0;
  if (t < 64) dg_cur = maskT[t];            // chunk 0 diag row (own lane's row)

  for (int c = 0; c < NW; ++c){
    if (t < 64){
      // prefetch chunk c+1's diag row + suppressor-row vs chunk c (coalesced)
      ull dg_nxt = 0, srow_nxt = 0;
      if (c+1 < NW){
        dg_nxt   = maskT[(size_t)(c+1)*NA + (size_t)(c+1)*64 + t];
        srow_nxt = maskT[(size_t)c*NA + (size_t)(c+1)*64 + t];
      }
      // phase A: register-only ballot fixpoint
      ull w0 = remv[c];
      bool dec  = ((w0 >> t) & 1ull) || ((srow_cur & kb_prev) != 0ull);
      bool kept = false;
      ull sup = dg_cur & ((1ull << t) - 1ull);   // earlier in-chunk suppressors
      for (;;){
        ull K = __ballot(kept);
        ull D = __ballot(dec);
        if (D == ~0ull) break;            // lowest undecided lane decides each round
        if (!dec){
          if (sup & K)                 { dec = true; }
          else if ((sup & ~D) == 0ull) { dec = true; kept = true; }
        }
      }
      ull kb = __ballot(kept);
      int cnt0 = cnt_sh;
      ull below = kb & ((1ull << t) - 1ull);
      int myrank = cnt0 + __popcll(below);
      if (kept && myrank < RPOST) selpos[myrank] = c*64 + t;
      if (t == 0){
        kb_sh[c & 1] = kb;
        keepw[c] = kb;
        int nc = cnt0 + __popcll(kb);
        if (nc >= RPOST){ nc = RPOST; done_sh = 1; }
        cnt_sh = nc;
      }
      kb_prev = kb; dg_cur = dg_nxt; srow_cur = srow_nxt;
    } else {
      // deferred phase B: kb(c-1) -> remv[c+1 ..] (one word/thread, unrolled)
      int u = t - 64;
      int wp = c + 1 + u;
      if (c >= 1 && wp < NW){
        ull kbp = kb_sh[(c-1) & 1];
        if (kbp){
          const ull* row = maskT + (size_t)wp*NA + (size_t)(c-1)*64;
          ull acc = remv[wp];
          #pragma unroll
          for (int b=0;b<64;++b)
            acc |= (0ull - ((kbp >> b) & 1ull)) & row[b];
          remv[wp] = acc;
        }
      }
    }
    __syncthreads();
    if (done_sh) break;                   // top-512 complete: uniform exit
  }
  __syncthreads();
  // parallel fill path (<512 kept after full scan): suppressed positions, ascending
  int cnt0 = cnt_sh;
  if (cnt0 < RPOST){
    if (t < NW){
      int s = 0;
      for (int w2=0; w2<t; ++w2) s += __popcll(~keepw[w2]);
      base_sh[t] = s;
    }
    __syncthreads();
    for (int p = t; p < NA; p += 256){
      int w2 = p >> 6, b = p & 63;
      ull kw = keepw[w2];
      if (!((kw >> b) & 1ull)){
        int rank = cnt0 + base_sh[w2] + __popcll(~kw & ((1ull << b) - 1ull));
        if (rank < RPOST) selpos[rank] = p;
      }
    }
  }
  __syncthreads();
  for (int s=t; s<RPOST; s+=256){
    int pos = selpos[s];
    int orig = ord[pos];
    float4 b = ((const float4*)sboxes)[pos];
    out[s*10+0] = probs[orig*2+0];
    out[s*10+1] = probs[orig*2+1];
    out[s*10+2] = b.x; out[s*10+3] = b.y; out[s*10+4] = b.z; out[s*10+5] = b.w;
    ((float4*)selb)[s] = b;
  }
}

// ---------------- K7: ROIAlign (block = box, thread = channel) -> bf16 pooled ----------------
__global__ __launch_bounds__(256) void roialign(const float* __restrict__ feat,
    const float* __restrict__ selb, __hip_bfloat16* __restrict__ pooled){
  int r = blockIdx.x, c = threadIdx.x;
  float4 b = ((const float4*)selb)[r];
  int x0[6], x1[6], y0[6], y1[6];
  float wx[6], wy[6];
  #pragma unroll
  for (int s=0;s<6;++s){
    float off = ((float)s + 0.5f) / 6.0f;
    float fx = (b.x + off*b.z) / 32.0f - 0.5f;
    fx = fminf(fmaxf(fx, 0.0f), 47.0f);
    int xx0 = (int)floorf(fx);
    x0[s] = xx0; x1[s] = min(xx0+1, 47); wx[s] = fx - (float)xx0;
    float fy = (b.y + off*b.w) / 32.0f - 0.5f;
    fy = fminf(fmaxf(fy, 0.0f), 47.0f);
    int yy0 = (int)floorf(fy);
    y0[s] = yy0; y1[s] = min(yy0+1, 47); wy[s] = fy - (float)yy0;
  }
  #pragma unroll
  for (int ty=0;ty<3;++ty){
    #pragma unroll
    for (int tx=0;tx<3;++tx){
      float sum = 0.0f;
      #pragma unroll
      for (int py=0;py<2;++py){
        #pragma unroll
        for (int px=0;px<2;++px){
          int sy = ty*2+py, sx = tx*2+px;
          float wxx = wx[sx], wyy = wy[sy];
          float v00 = feat[(y0[sy]*MGRID + x0[sx])*CCH + c];
          float v01 = feat[(y0[sy]*MGRID + x1[sx])*CCH + c];
          float v10 = feat[(y1[sy]*MGRID + x0[sx])*CCH + c];
          float v11 = feat[(y1[sy]*MGRID + x1[sx])*CCH + c];
          sum += v00*(1.0f-wyy)*(1.0f-wxx) + v01*(1.0f-wyy)*wxx
               + v10*wyy*(1.0f-wxx)        + v11*wyy*wxx;
        }
      }
      pooled[((r*9) + ty*3 + tx)*CCH + c] = __float2bfloat16(sum * 0.25f);
    }
  }
}

// ---------------- K8: FC1 bf16 MFMA, 2-way K-split ----------------
// grid (16,8,2): z selects K half [z*1152,(z+1)*1152). Partial (bias in z=0, NO relu)
// written to Hp + z*512*1024. fc2 sums the two partials and applies relu.
__global__ __launch_bounds__(256) void fc1_mfma(const ushort* __restrict__ A,
    const ushort* __restrict__ Bt, const float* __restrict__ bias,
    float* __restrict__ Hp){
  __shared__ ushort As[4096];   // 64 rows x 64 k bf16, XOR-swizzled 16B chunks
  __shared__ ushort Bs[4096];
  const int t = threadIdx.x;
  const int bn = blockIdx.x, bm = blockIdx.y, bz = blockIdx.z;
  const int wv = t >> 6, lane = t & 63;
  const int wm = (wv >> 1) * 32, wn = (wv & 1) * 32;

  // staging: 16B chunk s in {t, t+256}; row = s>>3, kchunk = s&7
  const int r0 = t >> 3, kc = t & 7;
  const int r1 = r0 + 32;
  const int kbase = bz * 144;   // 1152 k * 2B / 16B
  const float4* gA0 = (const float4*)A  + (size_t)(bm*64 + r0)*288 + kbase + kc;
  const float4* gA1 = (const float4*)A  + (size_t)(bm*64 + r1)*288 + kbase + kc;
  const float4* gB0 = (const float4*)Bt + (size_t)(bn*64 + r0)*288 + kbase + kc;
  const float4* gB1 = (const float4*)Bt + (size_t)(bn*64 + r1)*288 + kbase + kc;
  float4* sA0 = (float4*)As + ((r0<<3) | (kc ^ (r0&7)));
  float4* sA1 = (float4*)As + ((r1<<3) | (kc ^ (r1&7)));
  float4* sB0 = (float4*)Bs + ((r0<<3) | (kc ^ (r0&7)));
  float4* sB1 = (float4*)Bs + ((r1<<3) | (kc ^ (r1&7)));

  const int fr = lane & 15, fkg = lane >> 4;
  const int arow0 = wm + fr,      arow1 = wm + 16 + fr;
  const int brow0 = wn + fr,      brow1 = wn + 16 + fr;

  f32x4 acc00{}, acc01{}, acc10{}, acc11{};

  const int KT = 18;            // 1152 / 64
  float4 pa0 = gA0[0], pa1 = gA1[0], pb0 = gB0[0], pb1 = gB1[0];
  for (int kt = 0; kt < KT; ++kt){
    __syncthreads();                          // previous compute done; LDS writable
    *sA0 = pa0; *sA1 = pa1; *sB0 = pb0; *sB1 = pb1;
    if (kt + 1 < KT){                         // T14: issue next tile's loads early
      pa0 = gA0[(kt+1)*8]; pa1 = gA1[(kt+1)*8];
      pb0 = gB0[(kt+1)*8]; pb1 = gB1[(kt+1)*8];
    }
    __syncthreads();                          // LDS tile ready
    #pragma unroll
    for (int kk2 = 0; kk2 < 2; ++kk2){
      int kidx = fkg + kk2*4;
      short8v a0 = *(const short8v*)(As + ((((arow0<<3) | (kidx ^ (arow0&7)))) << 3));
      short8v a1 = *(const short8v*)(As + ((((arow1<<3) | (kidx ^ (arow1&7)))) << 3));
      short8v b0 = *(const short8v*)(Bs + ((((brow0<<3) | (kidx ^ (brow0&7)))) << 3));
      short8v b1 = *(const short8v*)(Bs + ((((brow1<<3) | (kidx ^ (brow1&7)))) << 3));
      acc00 = __builtin_amdgcn_mfma_f32_16x16x32_bf16(a0, b0, acc00, 0, 0, 0);
      acc01 = __builtin_amdgcn_mfma_f32_16x16x32_bf16(a0, b1, acc01, 0, 0, 0);
      acc10 = __builtin_amdgcn_mfma_f32_16x16x32_bf16(a1, b0, acc10, 0, 0, 0);
      acc11 = __builtin_amdgcn_mfma_f32_16x16x32_bf16(a1, b1, acc11, 0, 0, 0);
    }
  }
  // epilogue: C/D layout col=lane&15, row=(lane>>4)*4+reg  [m89/m91 verified]
  float* H = Hp + (size_t)bz * 512 * NHID;
  const int orow = bm*64 + wm + (lane>>4)*4;
  const int ocol = bn*64 + wn + (lane&15);
  #pragma unroll
  for (int i=0;i<2;++i){
    #pragma unroll
    for (int j=0;j<2;++j){
      f32x4 a = (i==0) ? ((j==0)?acc00:acc01) : ((j==0)?acc10:acc11);
      #pragma unroll
      for (int reg=0;reg<4;++reg){
        int row = orow + i*16 + reg;
        int col = ocol + j*16;
        float v = a[reg] + (bz == 0 ? bias[col] : 0.0f);
        H[(size_t)row*NHID + col] = v;        // relu deferred to fc2
      }
    }
  }
}

// ---------------- K9: FC2 (sums K-split partials + relu) + unparameterize ----------------
__global__ __launch_bounds__(64) void fc2(const float* __restrict__ h0,
    const float* __restrict__ h1, const float* __restrict__ W2,
    const float* __restrict__ b2, const float* __restrict__ selb,
    float* __restrict__ out){
  int r = blockIdx.x, lane = threadIdx.x;
  float a0=0,a1=0,a2=0,a3=0;
  #pragma unroll 4
  for (int it=0; it<16; ++it){
    int k = it*64 + lane;
    float hv = fmaxf(h0[(size_t)r*NHID + k] + h1[(size_t)r*NHID + k], 0.0f);
    float4 w = ((const float4*)W2)[k];
    a0 += hv*w.x; a1 += hv*w.y; a2 += hv*w.z; a3 += hv*w.w;
  }
  #pragma unroll
  for (int off=32; off>0; off>>=1){
    a0 += __shfl_down(a0, off);
    a1 += __shfl_down(a1, off);
    a2 += __shfl_down(a2, off);
    a3 += __shfl_down(a3, off);
  }
  if (lane == 0){
    float4 b = ((const float4*)selb)[r];
    float r0 = a0 + b2[0], r1 = a1 + b2[1], r2 = a2 + b2[2], r3 = a3 + b2[3];
    float cxa = b.x + b.z*0.5f, cya = b.y + b.w*0.5f;
    float cx = r0*b.z + cxa, cy = r1*b.w + cya;
    float w  = b.z*expf(r2),  hh = b.w*expf(r3);
    out[r*10+6] = cx - w*0.5f;
    out[r*10+7] = cy - hh*0.5f;
    out[r*10+8] = w;
    out[r*10+9] = hh;
  }
}

extern "C" void kernel_launch(void* const* d_in, const int* in_sizes, int n_in,
                              void* d_out, int out_size, void* d_ws, size_t ws_size,
                              hipStream_t stream) {
  const float* feat    = (const float*)d_in[0];
  const float* anchors = (const float*)d_in[1];
  const float* Wobj    = (const float*)d_in[2];
  const float* bobj    = (const float*)d_in[3];
  const float* Wreg    = (const float*)d_in[4];
  const float* breg    = (const float*)d_in[5];
  const float* Wfc1    = (const float*)d_in[6];
  const float* bfc1    = (const float*)d_in[7];
  const float* Wfc2    = (const float*)d_in[8];
  const float* bfc2    = (const float*)d_in[9];
  float* out = (float*)d_out;
  char* ws = (char*)d_ws;

  float* rpn    = (float*)(ws + 0);          // 165888
  float* probs  = (float*)(ws + 165888);     // 55296
  float* boxes  = (float*)(ws + 221184);     // 110592
  ull*   keys   = (ull*)  (ws + 331776);     // 55296
  int*   ord    = (int*)  (ws + 387072);     // 27648
  float* sboxes = (float*)(ws + 414720);     // 110592
  int*   part   = (int*)  (ws + 525312);     // 746496 (dead after rank_scatter)
  ull*   maskT  = (ull*)  (ws + 1271808);    // 5971968 (live through nms)
  float* selb   = (float*)(ws + 7243776);    // 8192
  __hip_bfloat16* pooled = (__hip_bfloat16*)(ws + 7251968); // 2359296
  float* h      = (float*)(ws + 9611264);    // 2x 2097152 = 4194304 (K-split partials)
  ushort* Wt    = (ushort*)(ws + 13805568);  // 4718592 (end 18524160)

  float* h0 = h;
  float* h1 = h + 512*NHID;

  hipLaunchKernelGGL(rpn_wcvt,     dim3(2466),    dim3(256), 0, stream, feat, Wobj, bobj, Wreg, breg, rpn, Wfc1, Wt);
  hipLaunchKernelGGL(anchor_prep,  dim3(27),      dim3(256), 0, stream, rpn, anchors, probs, boxes, keys);
  hipLaunchKernelGGL(rank_part,    dim3(27,27),   dim3(256), 0, stream, keys, part);
  hipLaunchKernelGGL(rank_scatter, dim3(27),      dim3(256), 0, stream, part, boxes, ord, sboxes);
  hipLaunchKernelGGL(iou_mask,     dim3(1499),    dim3(256), 0, stream, sboxes, maskT);
  hipLaunchKernelGGL(nms,          dim3(1),       dim3(256), 0, stream, maskT, ord, sboxes, probs, out, selb);
  hipLaunchKernelGGL(roialign,     dim3(512),     dim3(256), 0, stream, feat, selb, pooled);
  hipLaunchKernelGGL(fc1_mfma,     dim3(16,8,2),  dim3(256), 0, stream, (const ushort*)pooled, Wt, bfc1, h);
  hipLaunchKernelGGL(fc2,          dim3(512),     dim3(64),  0, stream, h0, h1, Wfc2, bfc2, selb, out);
}